// Round 4
// baseline (3411.897 us; speedup 1.0000x reference)
//
#include <hip/hip_runtime.h>
#include <math.h>

#define BB 8
#define SS 512
#define EE 1024
#define HH 16
#define DD 64
#define MLPD 4096
#define NROWS (BB*SS)      // 4096
#define LNEPS 1e-5f

// ---- scalar slots in workspace (amax values, all >= 0) ----
enum {
  SL_WQ=0, SL_WK, SL_WV, SL_WO, SL_W1, SL_W2,
  SL_BQ, SL_BK, SL_BV, SL_BO, SL_B1, SL_B2,
  SL_X, SL_Q, SL_K, SL_V, SL_SC, SL_AT, SL_CTX, SL_SDP,
  SL_LN1, SL_M1, SL_M2, SL_LN2, NSLOTS
};

__device__ __forceinline__ void atomicMaxF(float* a, float v) {
  // v >= 0 always: uint bit pattern ordering == float ordering
  atomicMax((unsigned int*)a, __float_as_uint(v));
}

// fake-quant one value: clip(rint(x/s), lo, hi) * s   (inv = 1/s)
__device__ __forceinline__ float fqv(float x, float inv, float s, float lo, float hi) {
  return fminf(fmaxf(rintf(x * inv), lo), hi) * s;
}

__global__ void k_init(float* scal) {
  if (threadIdx.x < NSLOTS) scal[threadIdx.x] = 0.f;
}

__global__ __launch_bounds__(256) void k_amax(const float* __restrict__ p, int n,
                                              float* scal, int slot) {
  float m = 0.f;
  for (int i = blockIdx.x * 256 + threadIdx.x; i < n; i += gridDim.x * 256)
    m = fmaxf(m, fabsf(p[i]));
  #pragma unroll
  for (int o = 32; o > 0; o >>= 1) m = fmaxf(m, __shfl_down(m, o, 64));
  __shared__ float red[4];
  int w = threadIdx.x >> 6;
  if ((threadIdx.x & 63) == 0) red[w] = m;
  __syncthreads();
  if (threadIdx.x == 0) {
    m = fmaxf(fmaxf(red[0], red[1]), fmaxf(red[2], red[3]));
    atomicMaxF(&scal[slot], m);
  }
}

// C[M,N] = fqA(A[M,K]) @ fqB(B[N,K])^T + fq(bias[N])
// aslot<0 => A raw.  B = weight (narrow +-127).  bias signed [-128,127].
// epi: 0 none, 1 abs-max, 2 relu-max  -> scal[epislot]
__global__ __launch_bounds__(256) void k_gemm_bt(
    const float* __restrict__ A, const float* __restrict__ Bw,
    const float* __restrict__ bias, float* __restrict__ C,
    int M, int N, int K, float* scal,
    int aslot, float adiv, float alo, float ahi,
    int bslot, int biasslot, int epi, int epislot)
{
  __shared__ float As[16][68];
  __shared__ float Bs[16][68];
  __shared__ float red[4];
  const int tx = threadIdx.x & 15, ty = threadIdx.x >> 4;
  const int m0 = blockIdx.y * 64, n0 = blockIdx.x * 64;

  float sA = 1.f, invA = 0.f;
  const bool qa = (aslot >= 0);
  if (qa) { sA = fmaxf(scal[aslot] / adiv, 1e-8f); invA = 1.f / sA; }
  const float sB = fmaxf(scal[bslot] / 127.f, 1e-8f), invB = 1.f / sB;

  float acc[4][4] = {{0.f}};
  for (int k0 = 0; k0 < K; k0 += 16) {
    #pragma unroll
    for (int p = 0; p < 4; ++p) {
      int e = threadIdx.x + p * 256;
      int r = e >> 4, c = e & 15;
      float v = A[(long)(m0 + r) * K + k0 + c];
      if (qa) v = fqv(v, invA, sA, alo, ahi);
      As[c][r] = v;
    }
    #pragma unroll
    for (int p = 0; p < 4; ++p) {
      int e = threadIdx.x + p * 256;
      int r = e >> 4, c = e & 15;
      float v = Bw[(long)(n0 + r) * K + k0 + c];
      Bs[c][r] = fqv(v, invB, sB, -127.f, 127.f);
    }
    __syncthreads();
    #pragma unroll
    for (int k = 0; k < 16; ++k) {
      float a[4], b[4];
      #pragma unroll
      for (int i = 0; i < 4; ++i) a[i] = As[k][ty + 16 * i];
      #pragma unroll
      for (int j = 0; j < 4; ++j) b[j] = Bs[k][tx + 16 * j];
      #pragma unroll
      for (int i = 0; i < 4; ++i)
        #pragma unroll
        for (int j = 0; j < 4; ++j)
          acc[i][j] += a[i] * b[j];
    }
    __syncthreads();
  }

  const float sb = fmaxf(scal[biasslot] / 127.f, 1e-8f), invb = 1.f / sb;
  float em = 0.f;
  #pragma unroll
  for (int j = 0; j < 4; ++j) {
    int col = n0 + tx + 16 * j;
    float bv = fqv(bias[col], invb, sb, -128.f, 127.f);
    #pragma unroll
    for (int i = 0; i < 4; ++i) {
      float c = acc[i][j] + bv;
      C[(long)(m0 + ty + 16 * i) * N + col] = c;
      if (epi == 1) em = fmaxf(em, fabsf(c));
      else if (epi == 2) em = fmaxf(em, c);
    }
  }
  if (epi) {
    #pragma unroll
    for (int o = 32; o > 0; o >>= 1) em = fmaxf(em, __shfl_down(em, o, 64));
    int w = threadIdx.x >> 6;
    if ((threadIdx.x & 63) == 0) red[w] = em;
    __syncthreads();
    if (threadIdx.x == 0)
      atomicMaxF(&scal[epislot], fmaxf(fmaxf(red[0], red[1]), fmaxf(red[2], red[3])));
  }
}

// scores[bh, q, k] = fq(q/8) . fq(k)   per head, K=64
__global__ __launch_bounds__(256) void k_scores(
    const float* __restrict__ q, const float* __restrict__ kk,
    float* __restrict__ sc, float* scal)
{
  __shared__ float Qs[64][65];
  __shared__ float Ks[64][65];
  __shared__ float red[4];
  const int bz = blockIdx.z, b = bz >> 4, h = bz & 15;
  const int tx = threadIdx.x & 15, ty = threadIdx.x >> 4;
  const int m0 = blockIdx.y * 64, n0 = blockIdx.x * 64;
  const long base = (long)b * SS * EE + h * DD;

  const float sq = fmaxf((scal[SL_Q] * 0.125f) / 127.f, 1e-8f), invq = 1.f / sq;
  const float sk = fmaxf(scal[SL_K] / 127.f, 1e-8f), invk = 1.f / sk;

  #pragma unroll
  for (int p = 0; p < 16; ++p) {
    int e = threadIdx.x + p * 256;
    int r = e >> 6, c = e & 63;
    float qv = q[base + (long)(m0 + r) * EE + c] * 0.125f;
    Qs[c][r] = fqv(qv, invq, sq, -128.f, 127.f);
    float kv = kk[base + (long)(n0 + r) * EE + c];
    Ks[c][r] = fqv(kv, invk, sk, -128.f, 127.f);
  }
  __syncthreads();

  float acc[4][4] = {{0.f}};
  #pragma unroll
  for (int kx = 0; kx < 64; ++kx) {
    float a[4], bv[4];
    #pragma unroll
    for (int i = 0; i < 4; ++i) a[i] = Qs[kx][ty + 16 * i];
    #pragma unroll
    for (int j = 0; j < 4; ++j) bv[j] = Ks[kx][tx + 16 * j];
    #pragma unroll
    for (int i = 0; i < 4; ++i)
      #pragma unroll
      for (int j = 0; j < 4; ++j)
        acc[i][j] += a[i] * bv[j];
  }

  float em = 0.f;
  #pragma unroll
  for (int i = 0; i < 4; ++i)
    #pragma unroll
    for (int j = 0; j < 4; ++j) {
      float c = acc[i][j];
      sc[((long)bz * SS + m0 + ty + 16 * i) * SS + n0 + tx + 16 * j] = c;
      em = fmaxf(em, fabsf(c));
    }
  #pragma unroll
  for (int o = 32; o > 0; o >>= 1) em = fmaxf(em, __shfl_down(em, o, 64));
  int w = threadIdx.x >> 6;
  if ((threadIdx.x & 63) == 0) red[w] = em;
  __syncthreads();
  if (threadIdx.x == 0)
    atomicMaxF(&scal[SL_SC], fmaxf(fmaxf(red[0], red[1]), fmaxf(red[2], red[3])));
}

// quantize scores, softmax each row (len 512) in place, track amax(attn)=max 1/denom
__global__ __launch_bounds__(256) void k_softmax(float* __restrict__ sc, float* scal) {
  float* p = sc + (long)blockIdx.x * SS;
  const float ss = fmaxf(scal[SL_SC] / 127.f, 1e-8f), inv = 1.f / ss;
  float v0 = fqv(p[threadIdx.x], inv, ss, -128.f, 127.f);
  float v1 = fqv(p[threadIdx.x + 256], inv, ss, -128.f, 127.f);

  __shared__ float red[4];
  __shared__ float red2[4];
  int w = threadIdx.x >> 6;
  float m = fmaxf(v0, v1);
  #pragma unroll
  for (int o = 32; o > 0; o >>= 1) m = fmaxf(m, __shfl_down(m, o, 64));
  if ((threadIdx.x & 63) == 0) red[w] = m;
  __syncthreads();
  m = fmaxf(fmaxf(red[0], red[1]), fmaxf(red[2], red[3]));

  float e0 = expf(v0 - m), e1 = expf(v1 - m);
  float s = e0 + e1;
  #pragma unroll
  for (int o = 32; o > 0; o >>= 1) s += __shfl_down(s, o, 64);
  if ((threadIdx.x & 63) == 0) red2[w] = s;
  __syncthreads();
  s = red2[0] + red2[1] + red2[2] + red2[3];

  p[threadIdx.x] = e0 / s;
  p[threadIdx.x + 256] = e1 / s;
  if (threadIdx.x == 0) atomicMaxF(&scal[SL_AT], 1.f / s);
}

// ctx[b, s, h*64+d] = fq(attn) @ fq(v)   per head, K = 512 (v NOT transposed)
__global__ __launch_bounds__(256) void k_ctx(
    const float* __restrict__ at, const float* __restrict__ v,
    float* __restrict__ ctx, float* scal)
{
  __shared__ float As[16][65];
  __shared__ float Vs[16][68];
  __shared__ float red[4];
  const int bz = blockIdx.y, b = bz >> 4, h = bz & 15;
  const int tx = threadIdx.x & 15, ty = threadIdx.x >> 4;
  const int m0 = blockIdx.x * 64;
  const long abase = (long)bz * SS * SS;
  const long vbase = (long)b * SS * EE + h * DD;

  const float sa = fmaxf(scal[SL_AT] / 127.f, 1e-8f), inva = 1.f / sa;
  const float sv = fmaxf(scal[SL_V] / 127.f, 1e-8f), invv = 1.f / sv;

  float acc[4][4] = {{0.f}};
  for (int k0 = 0; k0 < SS; k0 += 16) {
    #pragma unroll
    for (int p = 0; p < 4; ++p) {
      int e = threadIdx.x + p * 256;
      int r = e >> 4, c = e & 15;
      float a = at[abase + (long)(m0 + r) * SS + k0 + c];
      As[c][r] = fqv(a, inva, sa, -128.f, 127.f);
    }
    {
      int r = threadIdx.x >> 6, c = threadIdx.x & 63;
      #pragma unroll
      for (int p = 0; p < 4; ++p) {
        int rr = r + p * 4;
        float vv = v[vbase + (long)(k0 + rr) * EE + c];
        Vs[rr][c] = fqv(vv, invv, sv, -128.f, 127.f);
      }
    }
    __syncthreads();
    #pragma unroll
    for (int kx = 0; kx < 16; ++kx) {
      float a[4], bv[4];
      #pragma unroll
      for (int i = 0; i < 4; ++i) a[i] = As[kx][ty + 16 * i];
      #pragma unroll
      for (int j = 0; j < 4; ++j) bv[j] = Vs[kx][tx + 16 * j];
      #pragma unroll
      for (int i = 0; i < 4; ++i)
        #pragma unroll
        for (int j = 0; j < 4; ++j)
          acc[i][j] += a[i] * bv[j];
    }
    __syncthreads();
  }

  float em = 0.f;
  #pragma unroll
  for (int i = 0; i < 4; ++i)
    #pragma unroll
    for (int j = 0; j < 4; ++j) {
      float c = acc[i][j];
      ctx[((long)b * SS + m0 + ty + 16 * i) * EE + h * DD + tx + 16 * j] = c;
      em = fmaxf(em, fabsf(c));
    }
  #pragma unroll
  for (int o = 32; o > 0; o >>= 1) em = fmaxf(em, __shfl_down(em, o, 64));
  int w = threadIdx.x >> 6;
  if ((threadIdx.x & 63) == 0) red[w] = em;
  __syncthreads();
  if (threadIdx.x == 0)
    atomicMaxF(&scal[SL_CTX], fmaxf(fmaxf(red[0], red[1]), fmaxf(red[2], red[3])));
}

// out = layernorm(fq(A)+fq(B), g, be); store raw; amax -> scal[oslot]
__global__ __launch_bounds__(256) void k_ln(
    const float* __restrict__ A, const float* __restrict__ Bt,
    const float* __restrict__ g, const float* __restrict__ be,
    float* __restrict__ out, float* scal, int slotA, int slotB, int oslot)
{
  const long base = (long)blockIdx.x * EE;
  const float sa = fmaxf(scal[slotA] / 127.f, 1e-8f), ia = 1.f / sa;
  const float sb = fmaxf(scal[slotB] / 127.f, 1e-8f), ib = 1.f / sb;

  __shared__ float red[4];
  int w = threadIdx.x >> 6;

  float v[4];
  float sum = 0.f;
  #pragma unroll
  for (int p = 0; p < 4; ++p) {
    int c = threadIdx.x + p * 256;
    float av = fqv(A[base + c], ia, sa, -128.f, 127.f);
    float bv = fqv(Bt[base + c], ib, sb, -128.f, 127.f);
    v[p] = av + bv;
    sum += v[p];
  }
  #pragma unroll
  for (int o = 32; o > 0; o >>= 1) sum += __shfl_down(sum, o, 64);
  if ((threadIdx.x & 63) == 0) red[w] = sum;
  __syncthreads();
  float mu = (red[0] + red[1] + red[2] + red[3]) * (1.f / EE);

  float vs = 0.f;
  #pragma unroll
  for (int p = 0; p < 4; ++p) { float d = v[p] - mu; vs += d * d; }
  #pragma unroll
  for (int o = 32; o > 0; o >>= 1) vs += __shfl_down(vs, o, 64);
  __syncthreads();
  if ((threadIdx.x & 63) == 0) red[w] = vs;
  __syncthreads();
  float var = (red[0] + red[1] + red[2] + red[3]) * (1.f / EE);
  float rs = 1.f / sqrtf(var + LNEPS);

  float em = 0.f;
  #pragma unroll
  for (int p = 0; p < 4; ++p) {
    int c = threadIdx.x + p * 256;
    float o = (v[p] - mu) * rs * g[c] + be[c];
    out[base + c] = o;
    em = fmaxf(em, fabsf(o));
  }
  #pragma unroll
  for (int o = 32; o > 0; o >>= 1) em = fmaxf(em, __shfl_down(em, o, 64));
  __syncthreads();
  if ((threadIdx.x & 63) == 0) red[w] = em;
  __syncthreads();
  if (threadIdx.x == 0)
    atomicMaxF(&scal[oslot], fmaxf(fmaxf(red[0], red[1]), fmaxf(red[2], red[3])));
}

__global__ __launch_bounds__(256) void k_fq_out(float* __restrict__ o, float* scal) {
  const float s = fmaxf(scal[SL_LN2] / 127.f, 1e-8f), inv = 1.f / s;
  #pragma unroll
  for (int p = 0; p < 4; ++p) {
    long idx = (long)blockIdx.x * 1024 + threadIdx.x + p * 256;
    o[idx] = fqv(o[idx], inv, s, -128.f, 127.f);
  }
}

extern "C" void kernel_launch(void* const* d_in, const int* in_sizes, int n_in,
                              void* d_out, int out_size, void* d_ws, size_t ws_size,
                              hipStream_t stream) {
  (void)in_sizes; (void)n_in; (void)out_size; (void)ws_size;
  const float* x   = (const float*)d_in[0];
  const float* Wq  = (const float*)d_in[1];
  const float* bq  = (const float*)d_in[2];
  const float* Wk  = (const float*)d_in[3];
  const float* bk  = (const float*)d_in[4];
  const float* Wv  = (const float*)d_in[5];
  const float* bv  = (const float*)d_in[6];
  const float* Wo  = (const float*)d_in[7];
  const float* bo  = (const float*)d_in[8];
  const float* W1  = (const float*)d_in[9];
  const float* b1  = (const float*)d_in[10];
  const float* W2  = (const float*)d_in[11];
  const float* b2  = (const float*)d_in[12];
  const float* g1  = (const float*)d_in[13];
  const float* be1 = (const float*)d_in[14];
  const float* g2  = (const float*)d_in[15];
  const float* be2 = (const float*)d_in[16];
  float* out = (float*)d_out;

  float* scal = (float*)d_ws;
  float* qb  = scal + 256;
  float* kb  = qb + (long)NROWS * EE;
  float* vb  = kb + (long)NROWS * EE;
  float* sc  = vb + (long)NROWS * EE;          // B*H*S*S = 33.5M floats
  float* ctx = qb;                              // q dead after scores
  float* sdp = kb;                              // k dead after scores
  float* ln1 = vb;                              // v dead after ctx
  float* m1  = sc;                              // attn dead after ctx
  float* m2  = sc + (long)NROWS * MLPD;

  k_init<<<dim3(1), dim3(64), 0, stream>>>(scal);

  auto AM = [&](const float* p, long n, int slot) {
    int blocks = (int)((n + 255) / 256);
    if (blocks > 256) blocks = 256;
    k_amax<<<dim3(blocks), dim3(256), 0, stream>>>(p, (int)n, scal, slot);
  };
  AM(Wq, (long)EE * EE, SL_WQ); AM(Wk, (long)EE * EE, SL_WK);
  AM(Wv, (long)EE * EE, SL_WV); AM(Wo, (long)EE * EE, SL_WO);
  AM(W1, (long)MLPD * EE, SL_W1); AM(W2, (long)MLPD * EE, SL_W2);
  AM(bq, EE, SL_BQ); AM(bk, EE, SL_BK); AM(bv, EE, SL_BV); AM(bo, EE, SL_BO);
  AM(b1, MLPD, SL_B1); AM(b2, EE, SL_B2);
  AM(x, (long)NROWS * EE, SL_X);

  dim3 blk(256);
  // q, k, v projections: A = x (raw), B = W*, bias, epi abs-max
  k_gemm_bt<<<dim3(EE/64, NROWS/64), blk, 0, stream>>>(x, Wq, bq, qb, NROWS, EE, EE,
      scal, -1, 127.f, -128.f, 127.f, SL_WQ, SL_BQ, 1, SL_Q);
  k_gemm_bt<<<dim3(EE/64, NROWS/64), blk, 0, stream>>>(x, Wk, bk, kb, NROWS, EE, EE,
      scal, -1, 127.f, -128.f, 127.f, SL_WK, SL_BK, 1, SL_K);
  k_gemm_bt<<<dim3(EE/64, NROWS/64), blk, 0, stream>>>(x, Wv, bv, vb, NROWS, EE, EE,
      scal, -1, 127.f, -128.f, 127.f, SL_WV, SL_BV, 1, SL_V);

  k_scores<<<dim3(SS/64, SS/64, BB*HH), blk, 0, stream>>>(qb, kb, sc, scal);
  k_softmax<<<dim3(BB*HH*SS), blk, 0, stream>>>(sc, scal);
  k_ctx<<<dim3(SS/64, BB*HH), blk, 0, stream>>>(sc, vb, ctx, scal);

  // out-proj: A = ctx (fq signed), epi abs-max -> SL_SDP
  k_gemm_bt<<<dim3(EE/64, NROWS/64), blk, 0, stream>>>(ctx, Wo, bo, sdp, NROWS, EE, EE,
      scal, SL_CTX, 127.f, -128.f, 127.f, SL_WO, SL_BO, 1, SL_SDP);

  // h = fq(x)+fq(sdp) -> layernorm -> ln1 (raw) + amax
  k_ln<<<dim3(NROWS), blk, 0, stream>>>(x, sdp, g1, be1, ln1, scal, SL_X, SL_SDP, SL_LN1);

  // mlp1: A = ln1 (fq signed = h), epi relu-max -> SL_M1
  k_gemm_bt<<<dim3(MLPD/64, NROWS/64), blk, 0, stream>>>(ln1, W1, b1, m1, NROWS, MLPD, EE,
      scal, SL_LN1, 127.f, -128.f, 127.f, SL_W1, SL_B1, 2, SL_M1);

  // mlp2: A = m1 (fq unsigned 0..255), epi abs-max -> SL_M2
  k_gemm_bt<<<dim3(EE/64, NROWS/64), blk, 0, stream>>>(m1, W2, b2, m2, NROWS, EE, MLPD,
      scal, SL_M1, 255.f, 0.f, 255.f, SL_W2, SL_B2, 1, SL_M2);

  // y = fq(ln1)+fq(m2) -> layernorm -> d_out (raw) + amax
  k_ln<<<dim3(NROWS), blk, 0, stream>>>(ln1, m2, g2, be2, out, scal, SL_LN1, SL_M2, SL_LN2);

  // final per-tensor quantize of the output in place
  k_fq_out<<<dim3(NROWS), blk, 0, stream>>>(out, scal);
}

// Round 6
// 1668.135 us; speedup vs baseline: 2.0453x; 2.0453x over previous
//
#include <hip/hip_runtime.h>
#include <math.h>

#define BB 8
#define SS 512
#define EE 1024
#define HH 16
#define DD 64
#define MLPD 4096
#define NROWS (BB*SS)      // 4096
#define LNEPS 1e-5f

typedef unsigned short u16;
typedef __attribute__((ext_vector_type(8))) short bf8_t;   // 8 bf16 (4 VGPR)
typedef __attribute__((ext_vector_type(4))) float f32x4;

// ---- scalar slots in workspace (amax values, all >= 0) ----
enum {
  SL_WQ=0, SL_WK, SL_WV, SL_WO, SL_W1, SL_W2,
  SL_BQ, SL_BK, SL_BV, SL_BO, SL_B1, SL_B2,
  SL_X, SL_Q, SL_K, SL_V, SL_SC, SL_AT, SL_CTX, SL_SDP,
  SL_LN1, SL_M1, SL_M2, SL_LN2, NSLOTS
};

__device__ __forceinline__ void atomicMaxF(float* a, float v) {
  atomicMax((unsigned int*)a, __float_as_uint(v));   // v >= 0 always
}

__device__ __forceinline__ float fqv(float x, float inv, float s, float lo, float hi) {
  return fminf(fmaxf(rintf(x * inv), lo), hi) * s;
}

// float -> bf16 bits (RNE); exact for integers |v| <= 256
__device__ __forceinline__ u16 f2bf(float f) {
  unsigned int u = __float_as_uint(f);
  return (u16)((u + 0x7fffu + ((u >> 16) & 1u)) >> 16);
}
__device__ __forceinline__ float bf2f(u16 h) {
  return __uint_as_float((unsigned int)h << 16);
}

__device__ __forceinline__ void gll16(const void* src, void* dst) {
  // async global->LDS, 16B per lane; dst must be wave-uniform base
  __builtin_amdgcn_global_load_lds((const __attribute__((address_space(1))) void*)src,
                                   (__attribute__((address_space(3))) void*)dst, 16, 0, 0);
}

__global__ void k_init(float* scal) {
  if (threadIdx.x < NSLOTS) scal[threadIdx.x] = 0.f;
}

__global__ __launch_bounds__(256) void k_amax(const float* __restrict__ p, int n,
                                              float* scal, int slot) {
  float m = 0.f;
  for (int i = blockIdx.x * 256 + threadIdx.x; i < n; i += gridDim.x * 256)
    m = fmaxf(m, fabsf(p[i]));
  #pragma unroll
  for (int o = 32; o > 0; o >>= 1) m = fmaxf(m, __shfl_down(m, o, 64));
  __shared__ float red[4];
  int w = threadIdx.x >> 6;
  if ((threadIdx.x & 63) == 0) red[w] = m;
  __syncthreads();
  if (threadIdx.x == 0) {
    m = fmaxf(fmaxf(red[0], red[1]), fmaxf(red[2], red[3]));
    atomicMaxF(&scal[slot], m);
  }
}

// quantize float -> integer code stored as bf16 bits (exact)
__global__ __launch_bounds__(256) void k_conv_code(const float* __restrict__ in,
    u16* __restrict__ out, long n, const float* __restrict__ scal, int slot,
    float div, float lo, float hi)
{
  const float s = fmaxf(scal[slot] / div, 1e-8f), inv = 1.f / s;
  long i = ((long)blockIdx.x * 256 + threadIdx.x) * 4;
  const long stride = (long)gridDim.x * 1024;
  for (; i < n; i += stride) {
    const float4 v = *(const float4*)&in[i];
    ushort4 o;
    o.x = f2bf(fminf(fmaxf(rintf(v.x * inv), lo), hi));
    o.y = f2bf(fminf(fmaxf(rintf(v.y * inv), lo), hi));
    o.z = f2bf(fminf(fmaxf(rintf(v.z * inv), lo), hi));
    o.w = f2bf(fminf(fmaxf(rintf(v.w * inv), lo), hi));
    *(ushort4*)&out[i] = o;
  }
}

// raw float -> bf16 hi/lo split (x = hi + lo, residual ~2^-17)
__global__ __launch_bounds__(256) void k_conv_x(const float* __restrict__ in,
    u16* __restrict__ hi, u16* __restrict__ lo, long n)
{
  long i = ((long)blockIdx.x * 256 + threadIdx.x) * 4;
  const long stride = (long)gridDim.x * 1024;
  for (; i < n; i += stride) {
    const float4 v = *(const float4*)&in[i];
    ushort4 h, l;
    h.x = f2bf(v.x); l.x = f2bf(v.x - bf2f(h.x));
    h.y = f2bf(v.y); l.y = f2bf(v.y - bf2f(h.y));
    h.z = f2bf(v.z); l.z = f2bf(v.z - bf2f(h.z));
    h.w = f2bf(v.w); l.w = f2bf(v.w - bf2f(h.w));
    *(ushort4*)&hi[i] = h;
    *(ushort4*)&lo[i] = l;
  }
}

// C[M,N] = (A codes or xhi+xlo) @ Bcode[N,K]^T * (sA*sB) + fq(bias)
// 128x128 tile, BK=32, 4 waves (2x2) of 64x64; global_load_lds staging with
// inverse-swizzled source + XOR-swizzled ds_read_b128 (2-way conflict = free).
template<bool RAWX>
__global__ __launch_bounds__(256) void k_gemm_mfma(
    const u16* __restrict__ A0, const u16* __restrict__ A1,
    const u16* __restrict__ Bw, const float* __restrict__ bias,
    float* __restrict__ C, int M, int N, int K,
    const float* __restrict__ scal, float* scalw,
    int aslot, float adiv, int bslot, int biasslot, int epi, int epislot)
{
  __shared__ u16 As[128*32];
  __shared__ u16 Al[RAWX ? 128*32 : 16];
  __shared__ u16 Bs[128*32];
  __shared__ float red[4];

  const int t = threadIdx.x;
  const int w = t >> 6, lane = t & 63;
  const int wr = w >> 1, wc = w & 1;
  const int lr = lane & 15, cbl = lane >> 4;
  const int swz = (lr >> 1) & 3;
  const int m0 = blockIdx.y * 128, n0 = blockIdx.x * 128;

  // staging geometry: thread t, issue i in {0,1}: LDS 16B slot = i*256+t
  const int srow0 = t >> 2;                    // 0..63 (i=0); +64 (i=1)
  const int scb   = (t & 3) ^ ((srow0 >> 1) & 3);  // same for i=1 (row+64 keeps (row>>1)&3)
  const int lo0 = w * 512;                     // ushort offset of wave chunk, issue 0
  const int lo1 = 2048 + w * 512;              // issue 1
  const long arow0 = (long)(m0 + srow0)      * K + scb * 8;
  const long arow1 = (long)(m0 + srow0 + 64) * K + scb * 8;
  const long brow0 = (long)(n0 + srow0)      * K + scb * 8;
  const long brow1 = (long)(n0 + srow0 + 64) * K + scb * 8;

  // fragment LDS offsets (XOR-swizzled column block)
  int afo[4], bfo[4];
  #pragma unroll
  for (int i = 0; i < 4; ++i) {
    afo[i] = (wr*64 + i*16 + lr) * 32 + ((cbl ^ swz) * 8);
    bfo[i] = (wc*64 + i*16 + lr) * 32 + ((cbl ^ swz) * 8);
  }

  f32x4 acc[4][4] = {};

  for (int k0 = 0; k0 < K; k0 += 32) {
    gll16(A0 + arow0 + k0, As + lo0);
    gll16(A0 + arow1 + k0, As + lo1);
    if (RAWX) {
      gll16(A1 + arow0 + k0, Al + lo0);
      gll16(A1 + arow1 + k0, Al + lo1);
    }
    gll16(Bw + brow0 + k0, Bs + lo0);
    gll16(Bw + brow1 + k0, Bs + lo1);
    __syncthreads();   // drains vmcnt -> LDS valid

    bf8_t afr[4], bfr[4], alo[4];
    #pragma unroll
    for (int i = 0; i < 4; ++i) {
      afr[i] = *(const bf8_t*)&As[afo[i]];
      bfr[i] = *(const bf8_t*)&Bs[bfo[i]];
      if (RAWX) alo[i] = *(const bf8_t*)&Al[afo[i]];
    }
    #pragma unroll
    for (int i = 0; i < 4; ++i)
      #pragma unroll
      for (int j = 0; j < 4; ++j) {
        acc[i][j] = __builtin_amdgcn_mfma_f32_16x16x32_bf16(afr[i], bfr[j], acc[i][j], 0, 0, 0);
        if (RAWX)
          acc[i][j] = __builtin_amdgcn_mfma_f32_16x16x32_bf16(alo[i], bfr[j], acc[i][j], 0, 0, 0);
      }
    __syncthreads();   // protect LDS before next stage
  }

  float sA = 1.f;
  if (aslot >= 0) sA = fmaxf(scal[aslot] / adiv, 1e-8f);
  const float sB = fmaxf(scal[bslot] / 127.f, 1e-8f);
  const float sAB = sA * sB;
  const float sb = fmaxf(scal[biasslot] / 127.f, 1e-8f), invb = 1.f / sb;

  float em = 0.f;
  #pragma unroll
  for (int j = 0; j < 4; ++j) {
    const int col = n0 + wc*64 + j*16 + lr;
    const float bq = fqv(bias[col], invb, sb, -128.f, 127.f);
    #pragma unroll
    for (int i = 0; i < 4; ++i) {
      const int rowb = m0 + wr*64 + i*16 + cbl*4;   // D: row=(lane>>4)*4+reg, col=lane&15
      #pragma unroll
      for (int r = 0; r < 4; ++r) {
        const float c = acc[i][j][r] * sAB + bq;
        C[(long)(rowb + r) * N + col] = c;
        em = (epi == 2) ? fmaxf(em, c) : fmaxf(em, fabsf(c));
      }
    }
  }
  #pragma unroll
  for (int o = 32; o > 0; o >>= 1) em = fmaxf(em, __shfl_down(em, o, 64));
  if ((lane) == 0) red[w] = em;
  __syncthreads();
  if (t == 0)
    atomicMaxF(&scalw[epislot], fmaxf(fmaxf(red[0], red[1]), fmaxf(red[2], red[3])));
}

// scores[bh, q, k] = fq(q/8) . fq(k)   per head, K=64  (fp32 path, verified)
__global__ __launch_bounds__(256) void k_scores(
    const float* __restrict__ q, const float* __restrict__ kk,
    float* __restrict__ sc, float* scal)
{
  __shared__ float Qs[64][65];
  __shared__ float Ks[64][65];
  __shared__ float red[4];
  const int bz = blockIdx.z, b = bz >> 4, h = bz & 15;
  const int tx = threadIdx.x & 15, ty = threadIdx.x >> 4;
  const int m0 = blockIdx.y * 64, n0 = blockIdx.x * 64;
  const long base = (long)b * SS * EE + h * DD;

  const float sq = fmaxf((scal[SL_Q] * 0.125f) / 127.f, 1e-8f), invq = 1.f / sq;
  const float sk = fmaxf(scal[SL_K] / 127.f, 1e-8f), invk = 1.f / sk;

  #pragma unroll
  for (int p = 0; p < 16; ++p) {
    int e = threadIdx.x + p * 256;
    int r = e >> 6, c = e & 63;
    float qv = q[base + (long)(m0 + r) * EE + c] * 0.125f;
    Qs[c][r] = fqv(qv, invq, sq, -128.f, 127.f);
    float kv = kk[base + (long)(n0 + r) * EE + c];
    Ks[c][r] = fqv(kv, invk, sk, -128.f, 127.f);
  }
  __syncthreads();

  float acc[4][4] = {{0.f}};
  #pragma unroll
  for (int kx = 0; kx < 64; ++kx) {
    float a[4], bv[4];
    #pragma unroll
    for (int i = 0; i < 4; ++i) a[i] = Qs[kx][ty + 16 * i];
    #pragma unroll
    for (int j = 0; j < 4; ++j) bv[j] = Ks[kx][tx + 16 * j];
    #pragma unroll
    for (int i = 0; i < 4; ++i)
      #pragma unroll
      for (int j = 0; j < 4; ++j)
        acc[i][j] += a[i] * bv[j];
  }

  float em = 0.f;
  #pragma unroll
  for (int i = 0; i < 4; ++i)
    #pragma unroll
    for (int j = 0; j < 4; ++j) {
      float c = acc[i][j];
      sc[((long)bz * SS + m0 + ty + 16 * i) * SS + n0 + tx + 16 * j] = c;
      em = fmaxf(em, fabsf(c));
    }
  #pragma unroll
  for (int o = 32; o > 0; o >>= 1) em = fmaxf(em, __shfl_down(em, o, 64));
  int w = threadIdx.x >> 6;
  if ((threadIdx.x & 63) == 0) red[w] = em;
  __syncthreads();
  if (threadIdx.x == 0)
    atomicMaxF(&scal[SL_SC], fmaxf(fmaxf(red[0], red[1]), fmaxf(red[2], red[3])));
}

__global__ __launch_bounds__(256) void k_softmax(float* __restrict__ sc, float* scal) {
  float* p = sc + (long)blockIdx.x * SS;
  const float ss = fmaxf(scal[SL_SC] / 127.f, 1e-8f), inv = 1.f / ss;
  float v0 = fqv(p[threadIdx.x], inv, ss, -128.f, 127.f);
  float v1 = fqv(p[threadIdx.x + 256], inv, ss, -128.f, 127.f);

  __shared__ float red[4];
  __shared__ float red2[4];
  int w = threadIdx.x >> 6;
  float m = fmaxf(v0, v1);
  #pragma unroll
  for (int o = 32; o > 0; o >>= 1) m = fmaxf(m, __shfl_down(m, o, 64));
  if ((threadIdx.x & 63) == 0) red[w] = m;
  __syncthreads();
  m = fmaxf(fmaxf(red[0], red[1]), fmaxf(red[2], red[3]));

  float e0 = expf(v0 - m), e1 = expf(v1 - m);
  float s = e0 + e1;
  #pragma unroll
  for (int o = 32; o > 0; o >>= 1) s += __shfl_down(s, o, 64);
  if ((threadIdx.x & 63) == 0) red2[w] = s;
  __syncthreads();
  s = red2[0] + red2[1] + red2[2] + red2[3];

  p[threadIdx.x] = e0 / s;
  p[threadIdx.x + 256] = e1 / s;
  if (threadIdx.x == 0) atomicMaxF(&scal[SL_AT], 1.f / s);
}

// ctx = fq(attn) @ fq(v)  per head, K=512 (fp32 path, verified)
__global__ __launch_bounds__(256) void k_ctx(
    const float* __restrict__ at, const float* __restrict__ v,
    float* __restrict__ ctx, float* scal)
{
  __shared__ float As[16][65];
  __shared__ float Vs[16][68];
  __shared__ float red[4];
  const int bz = blockIdx.y, b = bz >> 4, h = bz & 15;
  const int tx = threadIdx.x & 15, ty = threadIdx.x >> 4;
  const int m0 = blockIdx.x * 64;
  const long abase = (long)bz * SS * SS;
  const long vbase = (long)b * SS * EE + h * DD;

  const float sa = fmaxf(scal[SL_AT] / 127.f, 1e-8f), inva = 1.f / sa;
  const float sv = fmaxf(scal[SL_V] / 127.f, 1e-8f), invv = 1.f / sv;

  float acc[4][4] = {{0.f}};
  for (int k0 = 0; k0 < SS; k0 += 16) {
    #pragma unroll
    for (int p = 0; p < 4; ++p) {
      int e = threadIdx.x + p * 256;
      int r = e >> 4, c = e & 15;
      float a = at[abase + (long)(m0 + r) * SS + k0 + c];
      As[c][r] = fqv(a, inva, sa, -128.f, 127.f);
    }
    {
      int r = threadIdx.x >> 6, c = threadIdx.x & 63;
      #pragma unroll
      for (int p = 0; p < 4; ++p) {
        int rr = r + p * 4;
        float vv = v[vbase + (long)(k0 + rr) * EE + c];
        Vs[rr][c] = fqv(vv, invv, sv, -128.f, 127.f);
      }
    }
    __syncthreads();
    #pragma unroll
    for (int kx = 0; kx < 16; ++kx) {
      float a[4], bv[4];
      #pragma unroll
      for (int i = 0; i < 4; ++i) a[i] = As[kx][ty + 16 * i];
      #pragma unroll
      for (int j = 0; j < 4; ++j) bv[j] = Vs[kx][tx + 16 * j];
      #pragma unroll
      for (int i = 0; i < 4; ++i)
        #pragma unroll
        for (int j = 0; j < 4; ++j)
          acc[i][j] += a[i] * bv[j];
    }
    __syncthreads();
  }

  float em = 0.f;
  #pragma unroll
  for (int i = 0; i < 4; ++i)
    #pragma unroll
    for (int j = 0; j < 4; ++j) {
      float c = acc[i][j];
      ctx[((long)b * SS + m0 + ty + 16 * i) * EE + h * DD + tx + 16 * j] = c;
      em = fmaxf(em, fabsf(c));
    }
  #pragma unroll
  for (int o = 32; o > 0; o >>= 1) em = fmaxf(em, __shfl_down(em, o, 64));
  int w = threadIdx.x >> 6;
  if ((threadIdx.x & 63) == 0) red[w] = em;
  __syncthreads();
  if (threadIdx.x == 0)
    atomicMaxF(&scal[SL_CTX], fmaxf(fmaxf(red[0], red[1]), fmaxf(red[2], red[3])));
}

__global__ __launch_bounds__(256) void k_ln(
    const float* __restrict__ A, const float* __restrict__ Bt,
    const float* __restrict__ g, const float* __restrict__ be,
    float* __restrict__ out, float* scal, int slotA, int slotB, int oslot)
{
  const long base = (long)blockIdx.x * EE;
  const float sa = fmaxf(scal[slotA] / 127.f, 1e-8f), ia = 1.f / sa;
  const float sb = fmaxf(scal[slotB] / 127.f, 1e-8f), ib = 1.f / sb;

  __shared__ float red[4];
  int w = threadIdx.x >> 6;

  float v[4];
  float sum = 0.f;
  #pragma unroll
  for (int p = 0; p < 4; ++p) {
    int c = threadIdx.x + p * 256;
    float av = fqv(A[base + c], ia, sa, -128.f, 127.f);
    float bv = fqv(Bt[base + c], ib, sb, -128.f, 127.f);
    v[p] = av + bv;
    sum += v[p];
  }
  #pragma unroll
  for (int o = 32; o > 0; o >>= 1) sum += __shfl_down(sum, o, 64);
  if ((threadIdx.x & 63) == 0) red[w] = sum;
  __syncthreads();
  float mu = (red[0] + red[1] + red[2] + red[3]) * (1.f / EE);

  float vs = 0.f;
  #pragma unroll
  for (int p = 0; p < 4; ++p) { float d = v[p] - mu; vs += d * d; }
  #pragma unroll
  for (int o = 32; o > 0; o >>= 1) vs += __shfl_down(vs, o, 64);
  __syncthreads();
  if ((threadIdx.x & 63) == 0) red[w] = vs;
  __syncthreads();
  float var = (red[0] + red[1] + red[2] + red[3]) * (1.f / EE);
  float rs = 1.f / sqrtf(var + LNEPS);

  float em = 0.f;
  #pragma unroll
  for (int p = 0; p < 4; ++p) {
    int c = threadIdx.x + p * 256;
    float o = (v[p] - mu) * rs * g[c] + be[c];
    out[base + c] = o;
    em = fmaxf(em, fabsf(o));
  }
  #pragma unroll
  for (int o = 32; o > 0; o >>= 1) em = fmaxf(em, __shfl_down(em, o, 64));
  __syncthreads();
  if ((threadIdx.x & 63) == 0) red[w] = em;
  __syncthreads();
  if (threadIdx.x == 0)
    atomicMaxF(&scal[oslot], fmaxf(fmaxf(red[0], red[1]), fmaxf(red[2], red[3])));
}

__global__ __launch_bounds__(256) void k_fq_out(float* __restrict__ o, float* scal) {
  const float s = fmaxf(scal[SL_LN2] / 127.f, 1e-8f), inv = 1.f / s;
  #pragma unroll
  for (int p = 0; p < 4; ++p) {
    long idx = (long)blockIdx.x * 1024 + threadIdx.x + p * 256;
    o[idx] = fqv(o[idx], inv, s, -128.f, 127.f);
  }
}

extern "C" void kernel_launch(void* const* d_in, const int* in_sizes, int n_in,
                              void* d_out, int out_size, void* d_ws, size_t ws_size,
                              hipStream_t stream) {
  (void)in_sizes; (void)n_in; (void)out_size; (void)ws_size;
  const float* x   = (const float*)d_in[0];
  const float* Wq  = (const float*)d_in[1];
  const float* bq  = (const float*)d_in[2];
  const float* Wk  = (const float*)d_in[3];
  const float* bk  = (const float*)d_in[4];
  const float* Wv  = (const float*)d_in[5];
  const float* bv  = (const float*)d_in[6];
  const float* Wo  = (const float*)d_in[7];
  const float* bo  = (const float*)d_in[8];
  const float* W1  = (const float*)d_in[9];
  const float* b1  = (const float*)d_in[10];
  const float* W2  = (const float*)d_in[11];
  const float* b2  = (const float*)d_in[12];
  const float* g1  = (const float*)d_in[13];
  const float* be1 = (const float*)d_in[14];
  const float* g2  = (const float*)d_in[15];
  const float* be2 = (const float*)d_in[16];
  float* out = (float*)d_out;

  // ---- workspace layout (bytes; total 192 MiB, lifetimes overlapped) ----
  char* W = (char*)d_ws;
  const long MB = 1024 * 1024;
  float* scal = (float*)W;                       // [0, 1MiB)
  u16* wqc  = (u16*)(W + 1*MB);                  // weight codes, persistent
  u16* wkc  = (u16*)(W + 3*MB);
  u16* wvc  = (u16*)(W + 5*MB);
  u16* woc  = (u16*)(W + 7*MB);                  // ends 9 MiB
  float* qb = (float*)(W + 16*MB);               // q / later ctx (fp32, 16 MiB)
  float* kb = (float*)(W + 32*MB);               // k / sdp / m2
  float* vb = (float*)(W + 48*MB);               // v / ln1
  float* sc = (float*)(W + 64*MB);               // scores region [64,192) MiB
  u16* xhi  = (u16*)(W + 64*MB);                 // during qkv only
  u16* xlo  = (u16*)(W + 72*MB);
  u16* ctxq = (u16*)(W + 64*MB);                 // after k_ctx
  u16* w1c  = (u16*)(W + 72*MB);                 // converted after attention
  u16* w2c  = (u16*)(W + 80*MB);
  u16* ln1q = (u16*)(W + 88*MB);
  float* m1 = (float*)(W + 96*MB);               // fp32, 64 MiB [96,160)
  u16* m1q  = (u16*)(W + 160*MB);                // 32 MiB [160,192)
  float* m2 = kb;

  k_init<<<dim3(1), dim3(64), 0, stream>>>(scal);

  auto AM = [&](const float* p, long n, int slot) {
    int blocks = (int)((n + 255) / 256);
    if (blocks > 256) blocks = 256;
    k_amax<<<dim3(blocks), dim3(256), 0, stream>>>(p, (int)n, scal, slot);
  };
  AM(Wq, (long)EE*EE, SL_WQ); AM(Wk, (long)EE*EE, SL_WK);
  AM(Wv, (long)EE*EE, SL_WV); AM(Wo, (long)EE*EE, SL_WO);
  AM(W1, (long)MLPD*EE, SL_W1); AM(W2, (long)MLPD*EE, SL_W2);
  AM(bq, EE, SL_BQ); AM(bk, EE, SL_BK); AM(bv, EE, SL_BV); AM(bo, EE, SL_BO);
  AM(b1, MLPD, SL_B1); AM(b2, EE, SL_B2);
  AM(x, (long)NROWS*EE, SL_X);

  auto CONV = [&](const float* in, u16* o, long n, int slot, float div, float lo, float hi) {
    int blocks = (int)(n / 1024);
    if (blocks > 2048) blocks = 2048;
    k_conv_code<<<dim3(blocks), dim3(256), 0, stream>>>(in, o, n, scal, slot, div, lo, hi);
  };

  // weight codes (narrow +-127)
  CONV(Wq, wqc, (long)EE*EE, SL_WQ, 127.f, -127.f, 127.f);
  CONV(Wk, wkc, (long)EE*EE, SL_WK, 127.f, -127.f, 127.f);
  CONV(Wv, wvc, (long)EE*EE, SL_WV, 127.f, -127.f, 127.f);
  CONV(Wo, woc, (long)EE*EE, SL_WO, 127.f, -127.f, 127.f);
  // x hi/lo split
  k_conv_x<<<dim3(2048), dim3(256), 0, stream>>>(x, xhi, xlo, (long)NROWS*EE);

  const dim3 blk(256);
  const dim3 gp(EE/128, NROWS/128);     // (8,32) proj GEMMs
  const dim3 gm1(MLPD/128, NROWS/128);  // (32,32)

  // q,k,v projections: raw-x MFMA (hi+lo), out = acc*sW + fq(bias)
  k_gemm_mfma<true><<<gp, blk, 0, stream>>>(xhi, xlo, wqc, bq, qb, NROWS, EE, EE,
      scal, scal, -1, 1.f, SL_WQ, SL_BQ, 1, SL_Q);
  k_gemm_mfma<true><<<gp, blk, 0, stream>>>(xhi, xlo, wkc, bk, kb, NROWS, EE, EE,
      scal, scal, -1, 1.f, SL_WK, SL_BK, 1, SL_K);
  k_gemm_mfma<true><<<gp, blk, 0, stream>>>(xhi, xlo, wvc, bv, vb, NROWS, EE, EE,
      scal, scal, -1, 1.f, SL_WV, SL_BV, 1, SL_V);

  // attention (fp32 verified path)
  k_scores<<<dim3(SS/64, SS/64, BB*HH), blk, 0, stream>>>(qb, kb, sc, scal);
  k_softmax<<<dim3(BB*HH*SS), blk, 0, stream>>>(sc, scal);
  k_ctx<<<dim3(SS/64, BB*HH), blk, 0, stream>>>(sc, vb, qb, scal);   // ctx -> qb

  // out-proj: quantize ctx, MFMA with Wo
  CONV(qb, ctxq, (long)NROWS*EE, SL_CTX, 127.f, -128.f, 127.f);
  CONV(W1, w1c, (long)MLPD*EE, SL_W1, 127.f, -127.f, 127.f);   // lazy (region free now)
  CONV(W2, w2c, (long)MLPD*EE, SL_W2, 127.f, -127.f, 127.f);
  k_gemm_mfma<false><<<gp, blk, 0, stream>>>(ctxq, ctxq, woc, bo, kb, NROWS, EE, EE,
      scal, scal, SL_CTX, 127.f, SL_WO, SL_BO, 1, SL_SDP);

  // h = fq(x)+fq(sdp) -> LN1 -> vb (raw) + amax
  k_ln<<<dim3(NROWS), blk, 0, stream>>>(x, kb, g1, be1, vb, scal, SL_X, SL_SDP, SL_LN1);

  // mlp1: quantize ln1, MFMA with W1 (relu-max epilogue)
  CONV(vb, ln1q, (long)NROWS*EE, SL_LN1, 127.f, -128.f, 127.f);
  k_gemm_mfma<false><<<gm1, blk, 0, stream>>>(ln1q, ln1q, w1c, b1, m1, NROWS, MLPD, EE,
      scal, scal, SL_LN1, 127.f, SL_W1, SL_B1, 2, SL_M1);

  // mlp2: quantize relu(m1) unsigned, MFMA with W2
  CONV(m1, m1q, (long)NROWS*MLPD, SL_M1, 255.f, 0.f, 255.f);
  k_gemm_mfma<false><<<gp, blk, 0, stream>>>(m1q, m1q, w2c, b2, m2, NROWS, EE, MLPD,
      scal, scal, SL_M1, 255.f, SL_W2, SL_B2, 1, SL_M2);

  // y = fq(ln1)+fq(m2) -> LN2 -> out + amax; final quantize
  k_ln<<<dim3(NROWS), blk, 0, stream>>>(vb, m2, g2, be2, out, scal, SL_LN1, SL_M2, SL_LN2);
  k_fq_out<<<dim3(NROWS), blk, 0, stream>>>(out, scal);
}

// Round 7
// 902.163 us; speedup vs baseline: 3.7819x; 1.8490x over previous
//
#include <hip/hip_runtime.h>
#include <math.h>

#define BB 8
#define SS 512
#define EE 1024
#define HH 16
#define DD 64
#define MLPD 4096
#define NROWS (BB*SS)      // 4096
#define LNEPS 1e-5f
#define SM_ROWS 8          // rows per wave in k_softmax
#define LN_ROWS 8          // rows per block in k_ln

typedef unsigned short u16;
typedef __attribute__((ext_vector_type(8))) short bf8_t;   // 8 bf16 (4 VGPR)
typedef __attribute__((ext_vector_type(4))) float f32x4;

// ---- scalar slots in workspace (amax values, all >= 0) ----
enum {
  SL_WQ=0, SL_WK, SL_WV, SL_WO, SL_W1, SL_W2,
  SL_BQ, SL_BK, SL_BV, SL_BO, SL_B1, SL_B2,
  SL_X, SL_Q, SL_K, SL_V, SL_SC, SL_AT, SL_CTX, SL_SDP,
  SL_LN1, SL_M1, SL_M2, SL_LN2, NSLOTS
};

__device__ __forceinline__ void atomicMaxF(float* a, float v) {
  atomicMax((unsigned int*)a, __float_as_uint(v));   // v >= 0 always
}

__device__ __forceinline__ float fqv(float x, float inv, float s, float lo, float hi) {
  return fminf(fmaxf(rintf(x * inv), lo), hi) * s;
}

// float -> bf16 bits (RNE); exact for integers |v| <= 256
__device__ __forceinline__ u16 f2bf(float f) {
  unsigned int u = __float_as_uint(f);
  return (u16)((u + 0x7fffu + ((u >> 16) & 1u)) >> 16);
}
__device__ __forceinline__ float bf2f(u16 h) {
  return __uint_as_float((unsigned int)h << 16);
}

__device__ __forceinline__ void gll16(const void* src, void* dst) {
  // async global->LDS, 16B per lane; dst must be wave-uniform base
  __builtin_amdgcn_global_load_lds((const __attribute__((address_space(1))) void*)src,
                                   (__attribute__((address_space(3))) void*)dst, 16, 0, 0);
}

__global__ void k_init(float* scal) {
  if (threadIdx.x < NSLOTS) scal[threadIdx.x] = 0.f;
}

__global__ __launch_bounds__(256) void k_amax(const float* __restrict__ p, int n,
                                              float* scal, int slot) {
  float m = 0.f;
  for (int i = blockIdx.x * 256 + threadIdx.x; i < n; i += gridDim.x * 256)
    m = fmaxf(m, fabsf(p[i]));
  #pragma unroll
  for (int o = 32; o > 0; o >>= 1) m = fmaxf(m, __shfl_down(m, o, 64));
  __shared__ float red[4];
  int w = threadIdx.x >> 6;
  if ((threadIdx.x & 63) == 0) red[w] = m;
  __syncthreads();
  if (threadIdx.x == 0) {
    m = fmaxf(fmaxf(red[0], red[1]), fmaxf(red[2], red[3]));
    atomicMaxF(&scal[slot], m);
  }
}

// quantize float -> integer code stored as bf16 bits (exact)
__global__ __launch_bounds__(256) void k_conv_code(const float* __restrict__ in,
    u16* __restrict__ out, long n, const float* __restrict__ scal, int slot,
    float div, float lo, float hi)
{
  const float s = fmaxf(scal[slot] / div, 1e-8f), inv = 1.f / s;
  long i = ((long)blockIdx.x * 256 + threadIdx.x) * 4;
  const long stride = (long)gridDim.x * 1024;
  for (; i < n; i += stride) {
    const float4 v = *(const float4*)&in[i];
    ushort4 o;
    o.x = f2bf(fminf(fmaxf(rintf(v.x * inv), lo), hi));
    o.y = f2bf(fminf(fmaxf(rintf(v.y * inv), lo), hi));
    o.z = f2bf(fminf(fmaxf(rintf(v.z * inv), lo), hi));
    o.w = f2bf(fminf(fmaxf(rintf(v.w * inv), lo), hi));
    *(ushort4*)&out[i] = o;
  }
}

// raw float -> bf16 hi/lo split (x = hi + lo, residual ~2^-17)
__global__ __launch_bounds__(256) void k_conv_x(const float* __restrict__ in,
    u16* __restrict__ hi, u16* __restrict__ lo, long n)
{
  long i = ((long)blockIdx.x * 256 + threadIdx.x) * 4;
  const long stride = (long)gridDim.x * 1024;
  for (; i < n; i += stride) {
    const float4 v = *(const float4*)&in[i];
    ushort4 h, l;
    h.x = f2bf(v.x); l.x = f2bf(v.x - bf2f(h.x));
    h.y = f2bf(v.y); l.y = f2bf(v.y - bf2f(h.y));
    h.z = f2bf(v.z); l.z = f2bf(v.z - bf2f(h.z));
    h.w = f2bf(v.w); l.w = f2bf(v.w - bf2f(h.w));
    *(ushort4*)&hi[i] = h;
    *(ushort4*)&lo[i] = l;
  }
}

// C[M,N] = (A codes or xhi+xlo) @ Bcode[N,K]^T * (sA*sB) + fq(bias)
// 128x128 tile, BK=32, 4 waves (2x2) of 64x64; global_load_lds staging with
// inverse-swizzled source + XOR-swizzled ds_read_b128 (2-way conflict = free).
template<bool RAWX>
__global__ __launch_bounds__(256) void k_gemm_mfma(
    const u16* __restrict__ A0, const u16* __restrict__ A1,
    const u16* __restrict__ Bw, const float* __restrict__ bias,
    float* __restrict__ C, int M, int N, int K,
    const float* __restrict__ scal, float* scalw,
    int aslot, float adiv, int bslot, int biasslot, int epi, int epislot)
{
  __shared__ u16 As[128*32];
  __shared__ u16 Al[RAWX ? 128*32 : 16];
  __shared__ u16 Bs[128*32];
  __shared__ float red[4];

  const int t = threadIdx.x;
  const int w = t >> 6, lane = t & 63;
  const int wr = w >> 1, wc = w & 1;
  const int lr = lane & 15, cbl = lane >> 4;
  const int swz = (lr >> 1) & 3;
  const int m0 = blockIdx.y * 128, n0 = blockIdx.x * 128;

  // staging geometry: thread t, issue i in {0,1}: LDS 16B slot = i*256+t
  const int srow0 = t >> 2;                    // 0..63 (i=0); +64 (i=1)
  const int scb   = (t & 3) ^ ((srow0 >> 1) & 3);  // same for i=1 (row+64 keeps (row>>1)&3)
  const int lo0 = w * 512;                     // ushort offset of wave chunk, issue 0
  const int lo1 = 2048 + w * 512;              // issue 1
  const long arow0 = (long)(m0 + srow0)      * K + scb * 8;
  const long arow1 = (long)(m0 + srow0 + 64) * K + scb * 8;
  const long brow0 = (long)(n0 + srow0)      * K + scb * 8;
  const long brow1 = (long)(n0 + srow0 + 64) * K + scb * 8;

  // fragment LDS offsets (XOR-swizzled column block)
  int afo[4], bfo[4];
  #pragma unroll
  for (int i = 0; i < 4; ++i) {
    afo[i] = (wr*64 + i*16 + lr) * 32 + ((cbl ^ swz) * 8);
    bfo[i] = (wc*64 + i*16 + lr) * 32 + ((cbl ^ swz) * 8);
  }

  f32x4 acc[4][4] = {};

  for (int k0 = 0; k0 < K; k0 += 32) {
    gll16(A0 + arow0 + k0, As + lo0);
    gll16(A0 + arow1 + k0, As + lo1);
    if (RAWX) {
      gll16(A1 + arow0 + k0, Al + lo0);
      gll16(A1 + arow1 + k0, Al + lo1);
    }
    gll16(Bw + brow0 + k0, Bs + lo0);
    gll16(Bw + brow1 + k0, Bs + lo1);
    __syncthreads();   // drains vmcnt -> LDS valid

    bf8_t afr[4], bfr[4], alo[4];
    #pragma unroll
    for (int i = 0; i < 4; ++i) {
      afr[i] = *(const bf8_t*)&As[afo[i]];
      bfr[i] = *(const bf8_t*)&Bs[bfo[i]];
      if (RAWX) alo[i] = *(const bf8_t*)&Al[afo[i]];
    }
    #pragma unroll
    for (int i = 0; i < 4; ++i)
      #pragma unroll
      for (int j = 0; j < 4; ++j) {
        acc[i][j] = __builtin_amdgcn_mfma_f32_16x16x32_bf16(afr[i], bfr[j], acc[i][j], 0, 0, 0);
        if (RAWX)
          acc[i][j] = __builtin_amdgcn_mfma_f32_16x16x32_bf16(alo[i], bfr[j], acc[i][j], 0, 0, 0);
      }
    __syncthreads();   // protect LDS before next stage
  }

  float sA = 1.f;
  if (aslot >= 0) sA = fmaxf(scal[aslot] / adiv, 1e-8f);
  const float sB = fmaxf(scal[bslot] / 127.f, 1e-8f);
  const float sAB = sA * sB;
  const float sb = fmaxf(scal[biasslot] / 127.f, 1e-8f), invb = 1.f / sb;

  float em = 0.f;
  #pragma unroll
  for (int j = 0; j < 4; ++j) {
    const int col = n0 + wc*64 + j*16 + lr;
    const float bq = fqv(bias[col], invb, sb, -128.f, 127.f);
    #pragma unroll
    for (int i = 0; i < 4; ++i) {
      const int rowb = m0 + wr*64 + i*16 + cbl*4;   // D: row=(lane>>4)*4+reg, col=lane&15
      #pragma unroll
      for (int r = 0; r < 4; ++r) {
        const float c = acc[i][j][r] * sAB + bq;
        C[(long)(rowb + r) * N + col] = c;
        em = (epi == 2) ? fmaxf(em, c) : fmaxf(em, fabsf(c));
      }
    }
  }
  #pragma unroll
  for (int o = 32; o > 0; o >>= 1) em = fmaxf(em, __shfl_down(em, o, 64));
  if ((lane) == 0) red[w] = em;
  __syncthreads();
  if (t == 0)
    atomicMaxF(&scalw[epislot], fmaxf(fmaxf(red[0], red[1]), fmaxf(red[2], red[3])));
}

// scores[bh, q, k] = fq(q/8) . fq(k)   per head, K=64  (fp32 path, verified)
__global__ __launch_bounds__(256) void k_scores(
    const float* __restrict__ q, const float* __restrict__ kk,
    float* __restrict__ sc, float* scal)
{
  __shared__ float Qs[64][65];
  __shared__ float Ks[64][65];
  __shared__ float red[4];
  const int bz = blockIdx.z, b = bz >> 4, h = bz & 15;
  const int tx = threadIdx.x & 15, ty = threadIdx.x >> 4;
  const int m0 = blockIdx.y * 64, n0 = blockIdx.x * 64;
  const long base = (long)b * SS * EE + h * DD;

  const float sq = fmaxf((scal[SL_Q] * 0.125f) / 127.f, 1e-8f), invq = 1.f / sq;
  const float sk = fmaxf(scal[SL_K] / 127.f, 1e-8f), invk = 1.f / sk;

  #pragma unroll
  for (int p = 0; p < 16; ++p) {
    int e = threadIdx.x + p * 256;
    int r = e >> 6, c = e & 63;
    float qv = q[base + (long)(m0 + r) * EE + c] * 0.125f;
    Qs[c][r] = fqv(qv, invq, sq, -128.f, 127.f);
    float kv = kk[base + (long)(n0 + r) * EE + c];
    Ks[c][r] = fqv(kv, invk, sk, -128.f, 127.f);
  }
  __syncthreads();

  float acc[4][4] = {{0.f}};
  #pragma unroll
  for (int kx = 0; kx < 64; ++kx) {
    float a[4], bv[4];
    #pragma unroll
    for (int i = 0; i < 4; ++i) a[i] = Qs[kx][ty + 16 * i];
    #pragma unroll
    for (int j = 0; j < 4; ++j) bv[j] = Ks[kx][tx + 16 * j];
    #pragma unroll
    for (int i = 0; i < 4; ++i)
      #pragma unroll
      for (int j = 0; j < 4; ++j)
        acc[i][j] += a[i] * bv[j];
  }

  float em = 0.f;
  #pragma unroll
  for (int i = 0; i < 4; ++i)
    #pragma unroll
    for (int j = 0; j < 4; ++j) {
      float c = acc[i][j];
      sc[((long)bz * SS + m0 + ty + 16 * i) * SS + n0 + tx + 16 * j] = c;
      em = fmaxf(em, fabsf(c));
    }
  #pragma unroll
  for (int o = 32; o > 0; o >>= 1) em = fmaxf(em, __shfl_down(em, o, 64));
  int w = threadIdx.x >> 6;
  if ((threadIdx.x & 63) == 0) red[w] = em;
  __syncthreads();
  if (threadIdx.x == 0)
    atomicMaxF(&scal[SL_SC], fmaxf(fmaxf(red[0], red[1]), fmaxf(red[2], red[3])));
}

// quantize scores, softmax rows in place; wave-per-row (8 rows/wave, 32/block).
// amax(attn) = max row 1/denom (row max quantized score -> exp(0)=1).
__global__ __launch_bounds__(256) void k_softmax(float* __restrict__ sc, float* scal) {
  const int w = threadIdx.x >> 6, lane = threadIdx.x & 63;
  const float ss = fmaxf(scal[SL_SC] / 127.f, 1e-8f), inv = 1.f / ss;
  float am = 0.f;
  long row = ((long)blockIdx.x * 4 + w) * SM_ROWS;
  for (int r = 0; r < SM_ROWS; ++r, ++row) {
    float4* p = (float4*)(sc + row * SS);
    float4 a = p[lane];
    float4 b = p[lane + 64];
    float v[8];
    v[0] = fqv(a.x, inv, ss, -128.f, 127.f);
    v[1] = fqv(a.y, inv, ss, -128.f, 127.f);
    v[2] = fqv(a.z, inv, ss, -128.f, 127.f);
    v[3] = fqv(a.w, inv, ss, -128.f, 127.f);
    v[4] = fqv(b.x, inv, ss, -128.f, 127.f);
    v[5] = fqv(b.y, inv, ss, -128.f, 127.f);
    v[6] = fqv(b.z, inv, ss, -128.f, 127.f);
    v[7] = fqv(b.w, inv, ss, -128.f, 127.f);
    float m = v[0];
    #pragma unroll
    for (int i = 1; i < 8; ++i) m = fmaxf(m, v[i]);
    #pragma unroll
    for (int o = 32; o > 0; o >>= 1) m = fmaxf(m, __shfl_xor(m, o, 64));
    float e[8], s = 0.f;
    #pragma unroll
    for (int i = 0; i < 8; ++i) { e[i] = expf(v[i] - m); s += e[i]; }
    #pragma unroll
    for (int o = 32; o > 0; o >>= 1) s += __shfl_xor(s, o, 64);
    const float rinv = 1.f / s;
    a.x = e[0] * rinv; a.y = e[1] * rinv; a.z = e[2] * rinv; a.w = e[3] * rinv;
    b.x = e[4] * rinv; b.y = e[5] * rinv; b.z = e[6] * rinv; b.w = e[7] * rinv;
    p[lane] = a;
    p[lane + 64] = b;
    am = fmaxf(am, rinv);
  }
  __shared__ float red[4];
  if (lane == 0) red[w] = am;
  __syncthreads();
  if (threadIdx.x == 0)
    atomicMaxF(&scal[SL_AT], fmaxf(fmaxf(red[0], red[1]), fmaxf(red[2], red[3])));
}

// ctx = fq(attn) @ fq(v)  per head, K=512 (fp32 path, verified)
__global__ __launch_bounds__(256) void k_ctx(
    const float* __restrict__ at, const float* __restrict__ v,
    float* __restrict__ ctx, float* scal)
{
  __shared__ float As[16][65];
  __shared__ float Vs[16][68];
  __shared__ float red[4];
  const int bz = blockIdx.y, b = bz >> 4, h = bz & 15;
  const int tx = threadIdx.x & 15, ty = threadIdx.x >> 4;
  const int m0 = blockIdx.x * 64;
  const long abase = (long)bz * SS * SS;
  const long vbase = (long)b * SS * EE + h * DD;

  const float sa = fmaxf(scal[SL_AT] / 127.f, 1e-8f), inva = 1.f / sa;
  const float sv = fmaxf(scal[SL_V] / 127.f, 1e-8f), invv = 1.f / sv;

  float acc[4][4] = {{0.f}};
  for (int k0 = 0; k0 < SS; k0 += 16) {
    #pragma unroll
    for (int p = 0; p < 4; ++p) {
      int e = threadIdx.x + p * 256;
      int r = e >> 4, c = e & 15;
      float a = at[abase + (long)(m0 + r) * SS + k0 + c];
      As[c][r] = fqv(a, inva, sa, -128.f, 127.f);
    }
    {
      int r = threadIdx.x >> 6, c = threadIdx.x & 63;
      #pragma unroll
      for (int p = 0; p < 4; ++p) {
        int rr = r + p * 4;
        float vv = v[vbase + (long)(k0 + rr) * EE + c];
        Vs[rr][c] = fqv(vv, invv, sv, -128.f, 127.f);
      }
    }
    __syncthreads();
    #pragma unroll
    for (int kx = 0; kx < 16; ++kx) {
      float a[4], bv[4];
      #pragma unroll
      for (int i = 0; i < 4; ++i) a[i] = As[kx][ty + 16 * i];
      #pragma unroll
      for (int j = 0; j < 4; ++j) bv[j] = Vs[kx][tx + 16 * j];
      #pragma unroll
      for (int i = 0; i < 4; ++i)
        #pragma unroll
        for (int j = 0; j < 4; ++j)
          acc[i][j] += a[i] * bv[j];
    }
    __syncthreads();
  }

  float em = 0.f;
  #pragma unroll
  for (int i = 0; i < 4; ++i)
    #pragma unroll
    for (int j = 0; j < 4; ++j) {
      float c = acc[i][j];
      ctx[((long)b * SS + m0 + ty + 16 * i) * EE + h * DD + tx + 16 * j] = c;
      em = fmaxf(em, fabsf(c));
    }
  #pragma unroll
  for (int o = 32; o > 0; o >>= 1) em = fmaxf(em, __shfl_down(em, o, 64));
  int w = threadIdx.x >> 6;
  if ((threadIdx.x & 63) == 0) red[w] = em;
  __syncthreads();
  if (threadIdx.x == 0)
    atomicMaxF(&scal[SL_CTX], fmaxf(fmaxf(red[0], red[1]), fmaxf(red[2], red[3])));
}

// out = layernorm(fq(A)+fq(B), g, be); LN_ROWS rows per block; one atomic/block
__global__ __launch_bounds__(256) void k_ln(
    const float* __restrict__ A, const float* __restrict__ Bt,
    const float* __restrict__ g, const float* __restrict__ be,
    float* __restrict__ out, float* scal, int slotA, int slotB, int oslot)
{
  const float sa = fmaxf(scal[slotA] / 127.f, 1e-8f), ia = 1.f / sa;
  const float sb = fmaxf(scal[slotB] / 127.f, 1e-8f), ib = 1.f / sb;

  __shared__ float red[4];
  const int w = threadIdx.x >> 6;
  float em = 0.f;

  for (int rr = 0; rr < LN_ROWS; ++rr) {
    const long base = ((long)blockIdx.x * LN_ROWS + rr) * EE;
    float v[4];
    float sum = 0.f;
    #pragma unroll
    for (int p = 0; p < 4; ++p) {
      int c = threadIdx.x + p * 256;
      float av = fqv(A[base + c], ia, sa, -128.f, 127.f);
      float bv = fqv(Bt[base + c], ib, sb, -128.f, 127.f);
      v[p] = av + bv;
      sum += v[p];
    }
    #pragma unroll
    for (int o = 32; o > 0; o >>= 1) sum += __shfl_down(sum, o, 64);
    if ((threadIdx.x & 63) == 0) red[w] = sum;
    __syncthreads();
    const float mu = (red[0] + red[1] + red[2] + red[3]) * (1.f / EE);
    __syncthreads();

    float vs = 0.f;
    #pragma unroll
    for (int p = 0; p < 4; ++p) { float d = v[p] - mu; vs += d * d; }
    #pragma unroll
    for (int o = 32; o > 0; o >>= 1) vs += __shfl_down(vs, o, 64);
    if ((threadIdx.x & 63) == 0) red[w] = vs;
    __syncthreads();
    const float var = (red[0] + red[1] + red[2] + red[3]) * (1.f / EE);
    const float rs = 1.f / sqrtf(var + LNEPS);
    __syncthreads();

    #pragma unroll
    for (int p = 0; p < 4; ++p) {
      int c = threadIdx.x + p * 256;
      float o = (v[p] - mu) * rs * g[c] + be[c];
      out[base + c] = o;
      em = fmaxf(em, fabsf(o));
    }
  }

  #pragma unroll
  for (int o = 32; o > 0; o >>= 1) em = fmaxf(em, __shfl_down(em, o, 64));
  if ((threadIdx.x & 63) == 0) red[w] = em;
  __syncthreads();
  if (threadIdx.x == 0)
    atomicMaxF(&scal[oslot], fmaxf(fmaxf(red[0], red[1]), fmaxf(red[2], red[3])));
}

__global__ __launch_bounds__(256) void k_fq_out(float* __restrict__ o, float* scal) {
  const float s = fmaxf(scal[SL_LN2] / 127.f, 1e-8f), inv = 1.f / s;
  #pragma unroll
  for (int p = 0; p < 4; ++p) {
    long idx = (long)blockIdx.x * 1024 + threadIdx.x + p * 256;
    o[idx] = fqv(o[idx], inv, s, -128.f, 127.f);
  }
}

extern "C" void kernel_launch(void* const* d_in, const int* in_sizes, int n_in,
                              void* d_out, int out_size, void* d_ws, size_t ws_size,
                              hipStream_t stream) {
  (void)in_sizes; (void)n_in; (void)out_size; (void)ws_size;
  const float* x   = (const float*)d_in[0];
  const float* Wq  = (const float*)d_in[1];
  const float* bq  = (const float*)d_in[2];
  const float* Wk  = (const float*)d_in[3];
  const float* bk  = (const float*)d_in[4];
  const float* Wv  = (const float*)d_in[5];
  const float* bv  = (const float*)d_in[6];
  const float* Wo  = (const float*)d_in[7];
  const float* bo  = (const float*)d_in[8];
  const float* W1  = (const float*)d_in[9];
  const float* b1  = (const float*)d_in[10];
  const float* W2  = (const float*)d_in[11];
  const float* b2  = (const float*)d_in[12];
  const float* g1  = (const float*)d_in[13];
  const float* be1 = (const float*)d_in[14];
  const float* g2  = (const float*)d_in[15];
  const float* be2 = (const float*)d_in[16];
  float* out = (float*)d_out;

  // ---- workspace layout (bytes; total 192 MiB, lifetimes overlapped) ----
  char* W = (char*)d_ws;
  const long MB = 1024 * 1024;
  float* scal = (float*)W;                       // [0, 1MiB)
  u16* wqc  = (u16*)(W + 1*MB);                  // weight codes, persistent
  u16* wkc  = (u16*)(W + 3*MB);
  u16* wvc  = (u16*)(W + 5*MB);
  u16* woc  = (u16*)(W + 7*MB);                  // ends 9 MiB
  float* qb = (float*)(W + 16*MB);               // q / later ctx (fp32, 16 MiB)
  float* kb = (float*)(W + 32*MB);               // k / sdp / m2
  float* vb = (float*)(W + 48*MB);               // v / ln1
  float* sc = (float*)(W + 64*MB);               // scores region [64,192) MiB
  u16* xhi  = (u16*)(W + 64*MB);                 // during qkv only
  u16* xlo  = (u16*)(W + 72*MB);
  u16* ctxq = (u16*)(W + 64*MB);                 // after k_ctx
  u16* w1c  = (u16*)(W + 72*MB);                 // converted after attention
  u16* w2c  = (u16*)(W + 80*MB);
  u16* ln1q = (u16*)(W + 88*MB);
  float* m1 = (float*)(W + 96*MB);               // fp32, 64 MiB [96,160)
  u16* m1q  = (u16*)(W + 160*MB);                // 32 MiB [160,192)
  float* m2 = kb;

  k_init<<<dim3(1), dim3(64), 0, stream>>>(scal);

  auto AM = [&](const float* p, long n, int slot) {
    int blocks = (int)((n + 255) / 256);
    if (blocks > 256) blocks = 256;
    k_amax<<<dim3(blocks), dim3(256), 0, stream>>>(p, (int)n, scal, slot);
  };
  AM(Wq, (long)EE*EE, SL_WQ); AM(Wk, (long)EE*EE, SL_WK);
  AM(Wv, (long)EE*EE, SL_WV); AM(Wo, (long)EE*EE, SL_WO);
  AM(W1, (long)MLPD*EE, SL_W1); AM(W2, (long)MLPD*EE, SL_W2);
  AM(bq, EE, SL_BQ); AM(bk, EE, SL_BK); AM(bv, EE, SL_BV); AM(bo, EE, SL_BO);
  AM(b1, MLPD, SL_B1); AM(b2, EE, SL_B2);
  AM(x, (long)NROWS*EE, SL_X);

  auto CONV = [&](const float* in, u16* o, long n, int slot, float div, float lo, float hi) {
    int blocks = (int)(n / 1024);
    if (blocks > 2048) blocks = 2048;
    k_conv_code<<<dim3(blocks), dim3(256), 0, stream>>>(in, o, n, scal, slot, div, lo, hi);
  };

  // weight codes (narrow +-127)
  CONV(Wq, wqc, (long)EE*EE, SL_WQ, 127.f, -127.f, 127.f);
  CONV(Wk, wkc, (long)EE*EE, SL_WK, 127.f, -127.f, 127.f);
  CONV(Wv, wvc, (long)EE*EE, SL_WV, 127.f, -127.f, 127.f);
  CONV(Wo, woc, (long)EE*EE, SL_WO, 127.f, -127.f, 127.f);
  // x hi/lo split
  k_conv_x<<<dim3(2048), dim3(256), 0, stream>>>(x, xhi, xlo, (long)NROWS*EE);

  const dim3 blk(256);
  const dim3 gp(EE/128, NROWS/128);     // (8,32) proj GEMMs
  const dim3 gm1(MLPD/128, NROWS/128);  // (32,32)

  // q,k,v projections: raw-x MFMA (hi+lo), out = acc*sW + fq(bias)
  k_gemm_mfma<true><<<gp, blk, 0, stream>>>(xhi, xlo, wqc, bq, qb, NROWS, EE, EE,
      scal, scal, -1, 1.f, SL_WQ, SL_BQ, 1, SL_Q);
  k_gemm_mfma<true><<<gp, blk, 0, stream>>>(xhi, xlo, wkc, bk, kb, NROWS, EE, EE,
      scal, scal, -1, 1.f, SL_WK, SL_BK, 1, SL_K);
  k_gemm_mfma<true><<<gp, blk, 0, stream>>>(xhi, xlo, wvc, bv, vb, NROWS, EE, EE,
      scal, scal, -1, 1.f, SL_WV, SL_BV, 1, SL_V);

  // attention (fp32 verified path)
  k_scores<<<dim3(SS/64, SS/64, BB*HH), blk, 0, stream>>>(qb, kb, sc, scal);
  k_softmax<<<dim3(BB*HH*SS/(4*SM_ROWS)), blk, 0, stream>>>(sc, scal);
  k_ctx<<<dim3(SS/64, BB*HH), blk, 0, stream>>>(sc, vb, qb, scal);   // ctx -> qb

  // out-proj: quantize ctx, MFMA with Wo
  CONV(qb, ctxq, (long)NROWS*EE, SL_CTX, 127.f, -128.f, 127.f);
  CONV(W1, w1c, (long)MLPD*EE, SL_W1, 127.f, -127.f, 127.f);   // lazy (region free now)
  CONV(W2, w2c, (long)MLPD*EE, SL_W2, 127.f, -127.f, 127.f);
  k_gemm_mfma<false><<<gp, blk, 0, stream>>>(ctxq, ctxq, woc, bo, kb, NROWS, EE, EE,
      scal, scal, SL_CTX, 127.f, SL_WO, SL_BO, 1, SL_SDP);

  // h = fq(x)+fq(sdp) -> LN1 -> vb (raw) + amax
  k_ln<<<dim3(NROWS/LN_ROWS), blk, 0, stream>>>(x, kb, g1, be1, vb, scal, SL_X, SL_SDP, SL_LN1);

  // mlp1: quantize ln1, MFMA with W1 (relu-max epilogue)
  CONV(vb, ln1q, (long)NROWS*EE, SL_LN1, 127.f, -128.f, 127.f);
  k_gemm_mfma<false><<<gm1, blk, 0, stream>>>(ln1q, ln1q, w1c, b1, m1, NROWS, MLPD, EE,
      scal, scal, SL_LN1, 127.f, SL_W1, SL_B1, 2, SL_M1);

  // mlp2: quantize relu(m1) unsigned, MFMA with W2
  CONV(m1, m1q, (long)NROWS*MLPD, SL_M1, 255.f, 0.f, 255.f);
  k_gemm_mfma<false><<<gp, blk, 0, stream>>>(m1q, m1q, w2c, b2, m2, NROWS, EE, MLPD,
      scal, scal, SL_M1, 255.f, SL_W2, SL_B2, 1, SL_M2);

  // y = fq(ln1)+fq(m2) -> LN2 -> out + amax; final quantize
  k_ln<<<dim3(NROWS/LN_ROWS), blk, 0, stream>>>(vb, m2, g2, be2, out, scal, SL_LN1, SL_M2, SL_LN2);
  k_fq_out<<<dim3(NROWS), blk, 0, stream>>>(out, scal);
}

// Round 13
// 837.742 us; speedup vs baseline: 4.0727x; 1.0769x over previous
//
#include <hip/hip_runtime.h>
#include <math.h>

#define BB 8
#define SS 512
#define EE 1024
#define HH 16
#define DD 64
#define MLPD 4096
#define NROWS (BB*SS)      // 4096
#define LNEPS 1e-5f
#define SM_ROWS 8          // rows per wave in k_softmax
#define LN_ROWS 8          // rows per block in k_ln

typedef unsigned short u16;
typedef __attribute__((ext_vector_type(8))) short bf8_t;   // 8 bf16 (4 VGPR)
typedef __attribute__((ext_vector_type(4))) float f32x4;

// ---- scalar slots in workspace (amax values, all >= 0) ----
enum {
  SL_WQ=0, SL_WK, SL_WV, SL_WO, SL_W1, SL_W2,
  SL_BQ, SL_BK, SL_BV, SL_BO, SL_B1, SL_B2,
  SL_X, SL_Q, SL_K, SL_V, SL_SC, SL_AT, SL_CTX, SL_SDP,
  SL_LN1, SL_M1, SL_M2, SL_LN2, NSLOTS
};

__device__ __forceinline__ void atomicMaxF(float* a, float v) {
  atomicMax((unsigned int*)a, __float_as_uint(v));   // v >= 0 always
}

__device__ __forceinline__ float fqv(float x, float inv, float s, float lo, float hi) {
  return fminf(fmaxf(rintf(x * inv), lo), hi) * s;
}

// float -> bf16 bits (RNE); exact for integers |v| <= 256
__device__ __forceinline__ u16 f2bf(float f) {
  unsigned int u = __float_as_uint(f);
  return (u16)((u + 0x7fffu + ((u >> 16) & 1u)) >> 16);
}
__device__ __forceinline__ float bf2f(u16 h) {
  return __uint_as_float((unsigned int)h << 16);
}

__device__ __forceinline__ void gll16(const void* src, void* dst) {
  // async global->LDS, 16B per lane; dst must be wave-uniform base
  __builtin_amdgcn_global_load_lds((const __attribute__((address_space(1))) void*)src,
                                   (__attribute__((address_space(3))) void*)dst, 16, 0, 0);
}

__global__ void k_init(float* scal) {
  if (threadIdx.x < NSLOTS) scal[threadIdx.x] = 0.f;
}

__global__ __launch_bounds__(256) void k_amax(const float* __restrict__ p, int n,
                                              float* scal, int slot) {
  float m = 0.f;
  for (int i = blockIdx.x * 256 + threadIdx.x; i < n; i += gridDim.x * 256)
    m = fmaxf(m, fabsf(p[i]));
  #pragma unroll
  for (int o = 32; o > 0; o >>= 1) m = fmaxf(m, __shfl_down(m, o, 64));
  __shared__ float red[4];
  int w = threadIdx.x >> 6;
  if ((threadIdx.x & 63) == 0) red[w] = m;
  __syncthreads();
  if (threadIdx.x == 0) {
    m = fmaxf(fmaxf(red[0], red[1]), fmaxf(red[2], red[3]));
    atomicMaxF(&scal[slot], m);
  }
}

// quantize float -> integer code stored as bf16 bits (exact).
// s = max(scal[slot]/div, 1e-8) * smul  (smul=8 for q: codes of q/8 at scale s/8)
__global__ __launch_bounds__(256) void k_conv_code(const float* __restrict__ in,
    u16* __restrict__ out, long n, const float* __restrict__ scal, int slot,
    float div, float smul, float lo, float hi)
{
  const float s = fmaxf(scal[slot] / div, 1e-8f) * smul, inv = 1.f / s;
  long i = ((long)blockIdx.x * 256 + threadIdx.x) * 4;
  const long stride = (long)gridDim.x * 1024;
  for (; i < n; i += stride) {
    const float4 v = *(const float4*)&in[i];
    ushort4 o;
    o.x = f2bf(fminf(fmaxf(rintf(v.x * inv), lo), hi));
    o.y = f2bf(fminf(fmaxf(rintf(v.y * inv), lo), hi));
    o.z = f2bf(fminf(fmaxf(rintf(v.z * inv), lo), hi));
    o.w = f2bf(fminf(fmaxf(rintf(v.w * inv), lo), hi));
    *(ushort4*)&out[i] = o;
  }
}

// raw float -> bf16 hi/lo split (x = hi + lo, residual ~2^-17)
__global__ __launch_bounds__(256) void k_conv_x(const float* __restrict__ in,
    u16* __restrict__ hi, u16* __restrict__ lo, long n)
{
  long i = ((long)blockIdx.x * 256 + threadIdx.x) * 4;
  const long stride = (long)gridDim.x * 1024;
  for (; i < n; i += stride) {
    const float4 v = *(const float4*)&in[i];
    ushort4 h, l;
    h.x = f2bf(v.x); l.x = f2bf(v.x - bf2f(h.x));
    h.y = f2bf(v.y); l.y = f2bf(v.y - bf2f(h.y));
    h.z = f2bf(v.z); l.z = f2bf(v.z - bf2f(h.z));
    h.w = f2bf(v.w); l.w = f2bf(v.w - bf2f(h.w));
    *(ushort4*)&hi[i] = h;
    *(ushort4*)&lo[i] = l;
  }
}

// V fp32 [b][s][h*64+d] -> codes transposed [bh][d][s]
__global__ __launch_bounds__(256) void k_conv_vt(
    const float* __restrict__ v, u16* __restrict__ vt, const float* __restrict__ scal)
{
  __shared__ u16 Ls[64][72];
  const int t = threadIdx.x;
  const int bz = blockIdx.y, b = bz >> 4, h = bz & 15;
  const int s0 = blockIdx.x * 64;
  const float sv = fmaxf(scal[SL_V] / 127.f, 1e-8f), inv = 1.f / sv;

  // read phase: thread (sl = t>>2, c4 = t&3) reads 16 d (4 float4)
  const int sl = t >> 2, c4 = t & 3;
  const long src = ((long)b * SS + s0 + sl) * EE + h * DD + c4 * 16;
  #pragma unroll
  for (int u = 0; u < 4; ++u) {
    const float4 x4 = *(const float4*)&v[src + u * 4];
    ushort4 o;
    o.x = f2bf(fminf(fmaxf(rintf(x4.x * inv), -128.f), 127.f));
    o.y = f2bf(fminf(fmaxf(rintf(x4.y * inv), -128.f), 127.f));
    o.z = f2bf(fminf(fmaxf(rintf(x4.z * inv), -128.f), 127.f));
    o.w = f2bf(fminf(fmaxf(rintf(x4.w * inv), -128.f), 127.f));
    *(ushort4*)&Ls[sl][c4 * 16 + u * 4] = o;
  }
  __syncthreads();
  // write phase: thread (d = t>>2, sg = t&3) writes 16 s of row d
  const int d = t >> 2, sg = t & 3;
  const long dst = ((long)bz * DD + d) * SS + s0 + sg * 16;
  #pragma unroll
  for (int u = 0; u < 4; ++u) {
    ushort4 o;
    o.x = Ls[sg * 16 + u * 4 + 0][d];
    o.y = Ls[sg * 16 + u * 4 + 1][d];
    o.z = Ls[sg * 16 + u * 4 + 2][d];
    o.w = Ls[sg * 16 + u * 4 + 3][d];
    *(ushort4*)&vt[dst + u * 4] = o;
  }
}

// C[M,N] = (A codes or xhi+xlo) @ Bcode[N,K]^T * (sA*sB) + fq(bias)
// 128x128 tile, BK=32, 4 waves (2x2) of 64x64; global_load_lds staging with
// inverse-swizzled source + XOR-swizzled ds_read_b128.
template<bool RAWX>
__global__ __launch_bounds__(256) void k_gemm_mfma(
    const u16* __restrict__ A0, const u16* __restrict__ A1,
    const u16* __restrict__ Bw, const float* __restrict__ bias,
    float* __restrict__ C, int M, int N, int K,
    const float* __restrict__ scal, float* scalw,
    int aslot, float adiv, int bslot, int biasslot, int epi, int epislot)
{
  __shared__ u16 As[128*32];
  __shared__ u16 Al[RAWX ? 128*32 : 16];
  __shared__ u16 Bs[128*32];
  __shared__ float red[4];

  const int t = threadIdx.x;
  const int w = t >> 6, lane = t & 63;
  const int wr = w >> 1, wc = w & 1;
  const int lr = lane & 15, cbl = lane >> 4;
  const int swz = (lr >> 1) & 3;
  const int m0 = blockIdx.y * 128, n0 = blockIdx.x * 128;

  const int srow0 = t >> 2;
  const int scb   = (t & 3) ^ ((srow0 >> 1) & 3);
  const int lo0 = w * 512;
  const int lo1 = 2048 + w * 512;
  const long arow0 = (long)(m0 + srow0)      * K + scb * 8;
  const long arow1 = (long)(m0 + srow0 + 64) * K + scb * 8;
  const long brow0 = (long)(n0 + srow0)      * K + scb * 8;
  const long brow1 = (long)(n0 + srow0 + 64) * K + scb * 8;

  int afo[4], bfo[4];
  #pragma unroll
  for (int i = 0; i < 4; ++i) {
    afo[i] = (wr*64 + i*16 + lr) * 32 + ((cbl ^ swz) * 8);
    bfo[i] = (wc*64 + i*16 + lr) * 32 + ((cbl ^ swz) * 8);
  }

  f32x4 acc[4][4] = {};

  for (int k0 = 0; k0 < K; k0 += 32) {
    gll16(A0 + arow0 + k0, As + lo0);
    gll16(A0 + arow1 + k0, As + lo1);
    if (RAWX) {
      gll16(A1 + arow0 + k0, Al + lo0);
      gll16(A1 + arow1 + k0, Al + lo1);
    }
    gll16(Bw + brow0 + k0, Bs + lo0);
    gll16(Bw + brow1 + k0, Bs + lo1);
    __syncthreads();

    bf8_t afr[4], bfr[4], alo[4];
    #pragma unroll
    for (int i = 0; i < 4; ++i) {
      afr[i] = *(const bf8_t*)&As[afo[i]];
      bfr[i] = *(const bf8_t*)&Bs[bfo[i]];
      if (RAWX) alo[i] = *(const bf8_t*)&Al[afo[i]];
    }
    #pragma unroll
    for (int i = 0; i < 4; ++i)
      #pragma unroll
      for (int j = 0; j < 4; ++j) {
        acc[i][j] = __builtin_amdgcn_mfma_f32_16x16x32_bf16(afr[i], bfr[j], acc[i][j], 0, 0, 0);
        if (RAWX)
          acc[i][j] = __builtin_amdgcn_mfma_f32_16x16x32_bf16(alo[i], bfr[j], acc[i][j], 0, 0, 0);
      }
    __syncthreads();
  }

  float sA = 1.f;
  if (aslot >= 0) sA = fmaxf(scal[aslot] / adiv, 1e-8f);
  const float sB = fmaxf(scal[bslot] / 127.f, 1e-8f);
  const float sAB = sA * sB;
  const float sb = fmaxf(scal[biasslot] / 127.f, 1e-8f), invb = 1.f / sb;

  float em = 0.f;
  #pragma unroll
  for (int j = 0; j < 4; ++j) {
    const int col = n0 + wc*64 + j*16 + lr;
    const float bq = fqv(bias[col], invb, sb, -128.f, 127.f);
    #pragma unroll
    for (int i = 0; i < 4; ++i) {
      const int rowb = m0 + wr*64 + i*16 + cbl*4;
      #pragma unroll
      for (int r = 0; r < 4; ++r) {
        const float c = acc[i][j][r] * sAB + bq;
        C[(long)(rowb + r) * N + col] = c;
        em = (epi == 2) ? fmaxf(em, c) : fmaxf(em, fabsf(c));
      }
    }
  }
  #pragma unroll
  for (int o = 32; o > 0; o >>= 1) em = fmaxf(em, __shfl_down(em, o, 64));
  if (lane == 0) red[w] = em;
  __syncthreads();
  if (t == 0)
    atomicMaxF(&scalw[epislot], fmaxf(fmaxf(red[0], red[1]), fmaxf(red[2], red[3])));
}

// scores[bh] = qcodes @ kcodes^T * (sq*sk); per-head strided rows (LDA=EE), K=64
__global__ __launch_bounds__(256) void k_scores_mfma(
    const u16* __restrict__ qc, const u16* __restrict__ kc,
    float* __restrict__ sc, float* scal)
{
  __shared__ u16 As[128*32];
  __shared__ u16 Bs[128*32];
  __shared__ float red[4];

  const int t = threadIdx.x;
  const int w = t >> 6, lane = t & 63;
  const int wr = w >> 1, wc = w & 1;
  const int lr = lane & 15, cbl = lane >> 4;
  const int swz = (lr >> 1) & 3;
  const int bz = blockIdx.z;
  const int m0 = blockIdx.y * 128, n0 = blockIdx.x * 128;
  const long base = (long)(bz >> 4) * SS * EE + (bz & 15) * DD;

  const int srow0 = t >> 2;
  const int scb   = (t & 3) ^ ((srow0 >> 1) & 3);
  const int lo0 = w * 512;
  const int lo1 = 2048 + w * 512;
  const long ar0 = base + (long)(m0 + srow0)      * EE + scb * 8;
  const long ar1 = base + (long)(m0 + srow0 + 64) * EE + scb * 8;
  const long br0 = base + (long)(n0 + srow0)      * EE + scb * 8;
  const long br1 = base + (long)(n0 + srow0 + 64) * EE + scb * 8;

  int afo[4], bfo[4];
  #pragma unroll
  for (int i = 0; i < 4; ++i) {
    afo[i] = (wr*64 + i*16 + lr) * 32 + ((cbl ^ swz) * 8);
    bfo[i] = (wc*64 + i*16 + lr) * 32 + ((cbl ^ swz) * 8);
  }

  f32x4 acc[4][4] = {};

  for (int k0 = 0; k0 < DD; k0 += 32) {
    gll16(qc + ar0 + k0, As + lo0);
    gll16(qc + ar1 + k0, As + lo1);
    gll16(kc + br0 + k0, Bs + lo0);
    gll16(kc + br1 + k0, Bs + lo1);
    __syncthreads();

    bf8_t afr[4], bfr[4];
    #pragma unroll
    for (int i = 0; i < 4; ++i) {
      afr[i] = *(const bf8_t*)&As[afo[i]];
      bfr[i] = *(const bf8_t*)&Bs[bfo[i]];
    }
    #pragma unroll
    for (int i = 0; i < 4; ++i)
      #pragma unroll
      for (int j = 0; j < 4; ++j)
        acc[i][j] = __builtin_amdgcn_mfma_f32_16x16x32_bf16(afr[i], bfr[j], acc[i][j], 0, 0, 0);
    __syncthreads();
  }

  const float sq = fmaxf(scal[SL_Q] / 1016.f, 1e-8f);   // == max((amax(q)/8)/127, 1e-8)
  const float sk = fmaxf(scal[SL_K] / 127.f, 1e-8f);
  const float sqk = sq * sk;

  float em = 0.f;
  #pragma unroll
  for (int j = 0; j < 4; ++j) {
    const int col = n0 + wc*64 + j*16 + lr;
    #pragma unroll
    for (int i = 0; i < 4; ++i) {
      const int rowb = m0 + wr*64 + i*16 + cbl*4;
      #pragma unroll
      for (int r = 0; r < 4; ++r) {
        const float c = acc[i][j][r] * sqk;
        sc[(long)bz * SS * SS + (long)(rowb + r) * SS + col] = c;
        em = fmaxf(em, fabsf(c));
      }
    }
  }
  #pragma unroll
  for (int o = 32; o > 0; o >>= 1) em = fmaxf(em, __shfl_down(em, o, 64));
  if (lane == 0) red[w] = em;
  __syncthreads();
  if (t == 0)
    atomicMaxF(&scal[SL_SC], fmaxf(fmaxf(red[0], red[1]), fmaxf(red[2], red[3])));
}

// quantize scores, softmax rows in place; wave-per-row (8 rows/wave, 32/block).
__global__ __launch_bounds__(256) void k_softmax(float* __restrict__ sc, float* scal) {
  const int w = threadIdx.x >> 6, lane = threadIdx.x & 63;
  const float ss = fmaxf(scal[SL_SC] / 127.f, 1e-8f), inv = 1.f / ss;
  float am = 0.f;
  long row = ((long)blockIdx.x * 4 + w) * SM_ROWS;
  for (int r = 0; r < SM_ROWS; ++r, ++row) {
    float4* p = (float4*)(sc + row * SS);
    float4 a = p[lane];
    float4 b = p[lane + 64];
    float v[8];
    v[0] = fqv(a.x, inv, ss, -128.f, 127.f);
    v[1] = fqv(a.y, inv, ss, -128.f, 127.f);
    v[2] = fqv(a.z, inv, ss, -128.f, 127.f);
    v[3] = fqv(a.w, inv, ss, -128.f, 127.f);
    v[4] = fqv(b.x, inv, ss, -128.f, 127.f);
    v[5] = fqv(b.y, inv, ss, -128.f, 127.f);
    v[6] = fqv(b.z, inv, ss, -128.f, 127.f);
    v[7] = fqv(b.w, inv, ss, -128.f, 127.f);
    float m = v[0];
    #pragma unroll
    for (int i = 1; i < 8; ++i) m = fmaxf(m, v[i]);
    #pragma unroll
    for (int o = 32; o > 0; o >>= 1) m = fmaxf(m, __shfl_xor(m, o, 64));
    float e[8], s = 0.f;
    #pragma unroll
    for (int i = 0; i < 8; ++i) { e[i] = expf(v[i] - m); s += e[i]; }
    #pragma unroll
    for (int o = 32; o > 0; o >>= 1) s += __shfl_xor(s, o, 64);
    const float rinv = 1.f / s;
    a.x = e[0] * rinv; a.y = e[1] * rinv; a.z = e[2] * rinv; a.w = e[3] * rinv;
    b.x = e[4] * rinv; b.y = e[5] * rinv; b.z = e[6] * rinv; b.w = e[7] * rinv;
    p[lane] = a;
    p[lane + 64] = b;
    am = fmaxf(am, rinv);
  }
  __shared__ float red[4];
  if (lane == 0) red[w] = am;
  __syncthreads();
  if (threadIdx.x == 0)
    atomicMaxF(&scal[SL_AT], fmaxf(fmaxf(red[0], red[1]), fmaxf(red[2], red[3])));
}

// ctx[b][s][h*64+d] = quant(attn) @ vt^T * (sa*sv); 128-row tile, 2x2 waves,
// A reg-staged (quantize probs fp32 -> codes, XOR-swizzled ds_write),
// B = vt codes [bh][d][s] via global_load_lds.
__global__ __launch_bounds__(256) void k_ctx_mfma(
    const float* __restrict__ at, const u16* __restrict__ vt,
    float* __restrict__ ctx, float* scal)
{
  __shared__ u16 As[128*32];   // 8 KB
  __shared__ u16 Bs[64*32];    // 4 KB
  __shared__ float red[4];

  const int t = threadIdx.x;
  const int w = t >> 6, lane = t & 63;
  const int wr = w >> 1, wc = w & 1;
  const int lr = lane & 15, cbl = lane >> 4;
  const int swz = (lr >> 1) & 3;
  const int bz = blockIdx.y, b = bz >> 4, h = bz & 15;
  const int m0 = blockIdx.x * 128;
  const long abase = (long)bz * SS * SS;
  const long vtbase = (long)bz * DD * SS;

  const float sa = fmaxf(scal[SL_AT] / 127.f, 1e-8f), inva = 1.f / sa;
  const float sv = fmaxf(scal[SL_V] / 127.f, 1e-8f);

  // B staging (global_load_lds 64x32): inverse-swizzled source, linear dst
  const int bsrow = t >> 2;
  const int bscb  = (t & 3) ^ ((bsrow >> 1) & 3);
  const long bsrc = vtbase + (long)bsrow * SS + bscb * 8;

  int afo[4], bfo[2];
  #pragma unroll
  for (int i = 0; i < 4; ++i)
    afo[i] = (wr*64 + i*16 + lr) * 32 + ((cbl ^ swz) * 8);
  #pragma unroll
  for (int j = 0; j < 2; ++j)
    bfo[j] = (wc*32 + j*16 + lr) * 32 + ((cbl ^ swz) * 8);

  f32x4 acc[4][2] = {};

  for (int k0 = 0; k0 < SS; k0 += 32) {
    gll16(vt + bsrc + k0, Bs + w * 512);
    // A: 128 rows x 32 k, reg-staged quantize; slot s: row=s>>3, c4=s&7 (4 floats)
    #pragma unroll
    for (int i = 0; i < 4; ++i) {
      const int s = i * 256 + t;
      const int row = s >> 3, c4 = s & 7;
      const float4 v4 = *(const float4*)&at[abase + (long)(m0 + row) * SS + k0 + c4 * 4];
      ushort4 o;
      o.x = f2bf(fminf(fmaxf(rintf(v4.x * inva), -128.f), 127.f));
      o.y = f2bf(fminf(fmaxf(rintf(v4.y * inva), -128.f), 127.f));
      o.z = f2bf(fminf(fmaxf(rintf(v4.z * inva), -128.f), 127.f));
      o.w = f2bf(fminf(fmaxf(rintf(v4.w * inva), -128.f), 127.f));
      const int off = row * 32 + (((c4 >> 1) ^ ((row >> 1) & 3)) * 8) + (c4 & 1) * 4;
      *(ushort4*)&As[off] = o;
    }
    __syncthreads();

    bf8_t afr[4], bfr[2];
    #pragma unroll
    for (int i = 0; i < 4; ++i) afr[i] = *(const bf8_t*)&As[afo[i]];
    #pragma unroll
    for (int j = 0; j < 2; ++j) bfr[j] = *(const bf8_t*)&Bs[bfo[j]];
    #pragma unroll
    for (int i = 0; i < 4; ++i)
      #pragma unroll
      for (int j = 0; j < 2; ++j)
        acc[i][j] = __builtin_amdgcn_mfma_f32_16x16x32_bf16(afr[i], bfr[j], acc[i][j], 0, 0, 0);
    __syncthreads();
  }

  const float sav = sa * sv;
  float em = 0.f;
  #pragma unroll
  for (int j = 0; j < 2; ++j) {
    const int col = h * DD + wc*32 + j*16 + lr;
    #pragma unroll
    for (int i = 0; i < 4; ++i) {
      const int rowb = m0 + wr*64 + i*16 + cbl*4;
      #pragma unroll
      for (int r = 0; r < 4; ++r) {
        const float c = acc[i][j][r] * sav;
        ctx[((long)b * SS + rowb + r) * EE + col] = c;
        em = fmaxf(em, fabsf(c));
      }
    }
  }
  #pragma unroll
  for (int o = 32; o > 0; o >>= 1) em = fmaxf(em, __shfl_down(em, o, 64));
  if (lane == 0) red[w] = em;
  __syncthreads();
  if (t == 0)
    atomicMaxF(&scal[SL_CTX], fmaxf(fmaxf(red[0], red[1]), fmaxf(red[2], red[3])));
}

// out = layernorm(fq(A)+fq(B), g, be); LN_ROWS rows per block; one atomic/block
__global__ __launch_bounds__(256) void k_ln(
    const float* __restrict__ A, const float* __restrict__ Bt,
    const float* __restrict__ g, const float* __restrict__ be,
    float* __restrict__ out, float* scal, int slotA, int slotB, int oslot)
{
  const float sa = fmaxf(scal[slotA] / 127.f, 1e-8f), ia = 1.f / sa;
  const float sb = fmaxf(scal[slotB] / 127.f, 1e-8f), ib = 1.f / sb;

  __shared__ float red[4];
  const int w = threadIdx.x >> 6;
  float em = 0.f;

  for (int rr = 0; rr < LN_ROWS; ++rr) {
    const long base = ((long)blockIdx.x * LN_ROWS + rr) * EE;
    float v[4];
    float sum = 0.f;
    #pragma unroll
    for (int p = 0; p < 4; ++p) {
      int c = threadIdx.x + p * 256;
      float av = fqv(A[base + c], ia, sa, -128.f, 127.f);
      float bv = fqv(Bt[base + c], ib, sb, -128.f, 127.f);
      v[p] = av + bv;
      sum += v[p];
    }
    #pragma unroll
    for (int o = 32; o > 0; o >>= 1) sum += __shfl_down(sum, o, 64);
    if ((threadIdx.x & 63) == 0) red[w] = sum;
    __syncthreads();
    const float mu = (red[0] + red[1] + red[2] + red[3]) * (1.f / EE);
    __syncthreads();

    float vs = 0.f;
    #pragma unroll
    for (int p = 0; p < 4; ++p) { float d = v[p] - mu; vs += d * d; }
    #pragma unroll
    for (int o = 32; o > 0; o >>= 1) vs += __shfl_down(vs, o, 64);
    if ((threadIdx.x & 63) == 0) red[w] = vs;
    __syncthreads();
    const float var = (red[0] + red[1] + red[2] + red[3]) * (1.f / EE);
    const float rs = 1.f / sqrtf(var + LNEPS);
    __syncthreads();

    #pragma unroll
    for (int p = 0; p < 4; ++p) {
      int c = threadIdx.x + p * 256;
      float o = (v[p] - mu) * rs * g[c] + be[c];
      out[base + c] = o;
      em = fmaxf(em, fabsf(o));
    }
  }

  #pragma unroll
  for (int o = 32; o > 0; o >>= 1) em = fmaxf(em, __shfl_down(em, o, 64));
  if ((threadIdx.x & 63) == 0) red[w] = em;
  __syncthreads();
  if (threadIdx.x == 0)
    atomicMaxF(&scal[oslot], fmaxf(fmaxf(red[0], red[1]), fmaxf(red[2], red[3])));
}

__global__ __launch_bounds__(256) void k_fq_out(float* __restrict__ o, float* scal) {
  const float s = fmaxf(scal[SL_LN2] / 127.f, 1e-8f), inv = 1.f / s;
  #pragma unroll
  for (int p = 0; p < 4; ++p) {
    long idx = (long)blockIdx.x * 1024 + threadIdx.x + p * 256;
    o[idx] = fqv(o[idx], inv, s, -128.f, 127.f);
  }
}

extern "C" void kernel_launch(void* const* d_in, const int* in_sizes, int n_in,
                              void* d_out, int out_size, void* d_ws, size_t ws_size,
                              hipStream_t stream) {
  (void)in_sizes; (void)n_in; (void)out_size; (void)ws_size;
  const float* x   = (const float*)d_in[0];
  const float* Wq  = (const float*)d_in[1];
  const float* bq  = (const float*)d_in[2];
  const float* Wk  = (const float*)d_in[3];
  const float* bk  = (const float*)d_in[4];
  const float* Wv  = (const float*)d_in[5];
  const float* bv  = (const float*)d_in[6];
  const float* Wo  = (const float*)d_in[7];
  const float* bo  = (const float*)d_in[8];
  const float* W1  = (const float*)d_in[9];
  const float* b1  = (const float*)d_in[10];
  const float* W2  = (const float*)d_in[11];
  const float* b2  = (const float*)d_in[12];
  const float* g1  = (const float*)d_in[13];
  const float* be1 = (const float*)d_in[14];
  const float* g2  = (const float*)d_in[15];
  const float* be2 = (const float*)d_in[16];
  float* out = (float*)d_out;

  // ---- workspace layout (MiB offsets; peak 184 MiB, lifetimes overlapped) ----
  char* W = (char*)d_ws;
  const long MB = 1024 * 1024;
  float* scal = (float*)W;                    // [0,1)
  u16* wqc  = (u16*)(W + 1*MB);               // [1,3) persistent weight codes
  u16* wkc  = (u16*)(W + 3*MB);
  u16* wvc  = (u16*)(W + 5*MB);
  u16* woc  = (u16*)(W + 7*MB);               // ends 9
  u16* xhi  = (u16*)(W + 16*MB);              // [16,24) dead after qkv
  u16* xlo  = (u16*)(W + 24*MB);              // [24,32)
  float* qb = (float*)(W + 48*MB);            // [48,64) q fp32, dead after qc conv
  float* kb = (float*)(W + 64*MB);            // [64,80)
  float* vb = (float*)(W + 80*MB);            // [80,96)
  u16* qc   = (u16*)(W + 144*MB);             // [144,152)
  u16* kc   = (u16*)(W + 152*MB);             // [152,160)
  u16* vt   = (u16*)(W + 160*MB);             // [160,168)
  float* sc = (float*)(W + 16*MB);            // [16,144) scores/probs (after qkv dead)
  float* ctxb = (float*)(W + 168*MB);         // [168,184)
  u16* ctxq = (u16*)(W + 144*MB);             // over qc (dead after scores)
  float* sdp = (float*)(W + 16*MB);           // over sc (dead after ctx)
  float* ln1 = (float*)(W + 32*MB);           // [32,48)
  u16* ln1q = (u16*)(W + 48*MB);              // over qb (dead)
  u16* w1c  = (u16*)(W + 56*MB);              // [56,64)
  u16* w2c  = (u16*)(W + 64*MB);              // over kb (dead)
  float* m1 = (float*)(W + 72*MB);            // [72,136)
  u16* m1q  = (u16*)(W + 136*MB);             // [136,168)
  float* m2 = (float*)(W + 168*MB);           // over ctxb (dead after ctxq conv)

  k_init<<<dim3(1), dim3(64), 0, stream>>>(scal);

  auto AM = [&](const float* p, long n, int slot) {
    int blocks = (int)((n + 255) / 256);
    if (blocks > 256) blocks = 256;
    k_amax<<<dim3(blocks), dim3(256), 0, stream>>>(p, (int)n, scal, slot);
  };
  AM(Wq, (long)EE*EE, SL_WQ); AM(Wk, (long)EE*EE, SL_WK);
  AM(Wv, (long)EE*EE, SL_WV); AM(Wo, (long)EE*EE, SL_WO);
  AM(W1, (long)MLPD*EE, SL_W1); AM(W2, (long)MLPD*EE, SL_W2);
  AM(bq, EE, SL_BQ); AM(bk, EE, SL_BK); AM(bv, EE, SL_BV); AM(bo, EE, SL_BO);
  AM(b1, MLPD, SL_B1); AM(b2, EE, SL_B2);
  AM(x, (long)NROWS*EE, SL_X);

  auto CONV = [&](const float* in, u16* o, long n, int slot, float div, float smul,
                  float lo, float hi) {
    int blocks = (int)(n / 1024);
    if (blocks > 2048) blocks = 2048;
    k_conv_code<<<dim3(blocks), dim3(256), 0, stream>>>(in, o, n, scal, slot, div, smul, lo, hi);
  };

  // weight codes (narrow +-127)
  CONV(Wq, wqc, (long)EE*EE, SL_WQ, 127.f, 1.f, -127.f, 127.f);
  CONV(Wk, wkc, (long)EE*EE, SL_WK, 127.f, 1.f, -127.f, 127.f);
  CONV(Wv, wvc, (long)EE*EE, SL_WV, 127.f, 1.f, -127.f, 127.f);
  CONV(Wo, woc, (long)EE*EE, SL_WO, 127.f, 1.f, -127.f, 127.f);
  // x hi/lo split
  k_conv_x<<<dim3(2048), dim3(256), 0, stream>>>(x, xhi, xlo, (long)NROWS*EE);

  const dim3 blk(256);
  const dim3 gp(EE/128, NROWS/128);     // (8,32) proj GEMMs
  const dim3 gm1(MLPD/128, NROWS/128);  // (32,32)

  // q,k,v projections
  k_gemm_mfma<true><<<gp, blk, 0, stream>>>(xhi, xlo, wqc, bq, qb, NROWS, EE, EE,
      scal, scal, -1, 1.f, SL_WQ, SL_BQ, 1, SL_Q);
  k_gemm_mfma<true><<<gp, blk, 0, stream>>>(xhi, xlo, wkc, bk, kb, NROWS, EE, EE,
      scal, scal, -1, 1.f, SL_WK, SL_BK, 1, SL_K);
  k_gemm_mfma<true><<<gp, blk, 0, stream>>>(xhi, xlo, wvc, bv, vb, NROWS, EE, EE,
      scal, scal, -1, 1.f, SL_WV, SL_BV, 1, SL_V);

  // attention codes: q (scale of q/8 folded: div=1016, smul=8), k, v-transposed
  CONV(qb, qc, (long)NROWS*EE, SL_Q, 1016.f, 8.f, -128.f, 127.f);
  CONV(kb, kc, (long)NROWS*EE, SL_K, 127.f, 1.f, -128.f, 127.f);
  k_conv_vt<<<dim3(SS/64, BB*HH), blk, 0, stream>>>(vb, vt, scal);

  // attention (MFMA path)
  k_scores_mfma<<<dim3(SS/128, SS/128, BB*HH), blk, 0, stream>>>(qc, kc, sc, scal);
  k_softmax<<<dim3(BB*HH*SS/(4*SM_ROWS)), blk, 0, stream>>>(sc, scal);
  k_ctx_mfma<<<dim3(SS/128, BB*HH), blk, 0, stream>>>(sc, vt, ctxb, scal);

  // out-proj
  CONV(ctxb, ctxq, (long)NROWS*EE, SL_CTX, 127.f, 1.f, -128.f, 127.f);
  CONV(W1, w1c, (long)MLPD*EE, SL_W1, 127.f, 1.f, -127.f, 127.f);
  CONV(W2, w2c, (long)MLPD*EE, SL_W2, 127.f, 1.f, -127.f, 127.f);
  k_gemm_mfma<false><<<gp, blk, 0, stream>>>(ctxq, ctxq, woc, bo, sdp, NROWS, EE, EE,
      scal, scal, SL_CTX, 127.f, SL_WO, SL_BO, 1, SL_SDP);

  // h = fq(x)+fq(sdp) -> LN1 -> ln1 + amax
  k_ln<<<dim3(NROWS/LN_ROWS), blk, 0, stream>>>(x, sdp, g1, be1, ln1, scal, SL_X, SL_SDP, SL_LN1);

  // mlp1
  CONV(ln1, ln1q, (long)NROWS*EE, SL_LN1, 127.f, 1.f, -128.f, 127.f);
  k_gemm_mfma<false><<<gm1, blk, 0, stream>>>(ln1q, ln1q, w1c, b1, m1, NROWS, MLPD, EE,
      scal, scal, SL_LN1, 127.f, SL_W1, SL_B1, 2, SL_M1);

  // mlp2
  CONV(m1, m1q, (long)NROWS*MLPD, SL_M1, 255.f, 1.f, 0.f, 255.f);
  k_gemm_mfma<false><<<gp, blk, 0, stream>>>(m1q, m1q, w2c, b2, m2, NROWS, EE, MLPD,
      scal, scal, SL_M1, 255.f, SL_W2, SL_B2, 1, SL_M2);

  // y = fq(ln1)+fq(m2) -> LN2 -> out + amax; final quantize
  k_ln<<<dim3(NROWS/LN_ROWS), blk, 0, stream>>>(ln1, m2, g2, be2, out, scal, SL_LN1, SL_M2, SL_LN2);
  k_fq_out<<<dim3(NROWS), blk, 0, stream>>>(out, scal);
}